// Round 16
// baseline (593.804 us; speedup 1.0000x reference)
//
#include <hip/hip_runtime.h>
#include <math.h>

typedef unsigned short ushort_t;
typedef unsigned int uint_t;
typedef unsigned long long u64_t;
typedef __bf16 bf16x8_t __attribute__((ext_vector_type(8)));
typedef float f32x4_t __attribute__((ext_vector_type(4)));

static constexpr int NPTS = 1024;
static constexpr int NB = 64;
static constexpr int NPOINTS = NB * NPTS;   // 65536
static constexpr int KNB = 16;
static constexpr int NCHUNK2 = 4;           // mfma knn chunking

__device__ __forceinline__ ushort_t f2bf(float f) {
    uint_t u = __float_as_uint(f);
    uint_t r = (u + 0x7FFFu + ((u >> 16) & 1u)) >> 16;
    return (ushort_t)r;
}
// pack distance (clamped >=0, 22 bits kept) + batch-local j (10 bits).
__device__ __forceinline__ uint_t packdj(float d, int j) {
    return (__float_as_uint(fmaxf(d, 0.f)) & 0xFFFFFC00u) | (uint_t)j;
}
// single-instruction median: for sorted L[k-1]<=L[k], post-insert
// L'[k] = med3(L[k-1], L[k], c). One VOP3 per step; all steps independent.
__device__ __forceinline__ uint_t med3u(uint_t a, uint_t b, uint_t c) {
    uint_t d;
    asm("v_med3_u32 %0, %1, %2, %3" : "=v"(d) : "v"(a), "v"(b), "v"(c));
    return d;
}
__device__ __forceinline__ void insert16(uint_t* L, uint_t c) {
    #pragma unroll
    for (int k = 15; k > 0; --k)
        L[k] = med3u(L[k - 1], L[k], c);
    L[0] = L[0] < c ? L[0] : c;
}
// monotone float->uint order transform
__device__ __forceinline__ uint_t f2ord(float f) {
    uint_t u = __float_as_uint(f);
    return (u & 0x80000000u) ? ~u : (u ^ 0x80000000u);
}

// ---------------- fused weight prep: w1 (frag-contig) + 3x w2 (frag-contig) ----------------
__global__ __launch_bounds__(256) void prep_kernel(const float* __restrict__ mw1,
                                                   const float* __restrict__ c1w2,
                                                   const float* __restrict__ c2w2,
                                                   const float* __restrict__ c3w2,
                                                   ushort_t* __restrict__ w1fh,
                                                   ushort_t* __restrict__ w1fl,
                                                   ushort_t* __restrict__ w2fh,  // 3 layers concat
                                                   ushort_t* __restrict__ w2fl) {
    int blk = blockIdx.x;
    if (blk < 96) {
        int t = blk * 256 + threadIdx.x;         // 0..24575
        int e = t & 7;
        int lane = (t >> 3) & 63;
        int fs = t >> 9;                         // frag id = nt*6+ks, 0..47
        int nt = fs / 6, ks = fs - nt * 6;
        int m = lane & 15, quad = lane >> 4;
        int k = ks * 32 + quad * 8 + e;
        int n = nt * 16 + m;
        float w = mw1[k * 128 + n];
        uint_t bits = __float_as_uint(w);
        float hif = __uint_as_float(bits & 0xFFFF0000u);
        w1fh[t] = (ushort_t)(bits >> 16);
        w1fl[t] = f2bf(w - hif);
    } else {
        int layer = (blk - 96) >> 4;             // 0..2
        const float* w2 = layer == 0 ? c1w2 : (layer == 1 ? c2w2 : c3w2);
        int t = ((blk - 96) & 15) * 256 + threadIdx.x;   // 0..4095
        int e = t & 7;
        int lane = (t >> 3) & 63;
        int fs = t >> 9;                         // frag id = ct*2+kh, 0..7
        int ct = fs >> 1, kh = fs & 1;
        int m = lane & 15, quad = lane >> 4;
        int k = kh * 32 + quad * 8 + e;
        int n = ct * 16 + m;
        float w = w2[k * 64 + n];
        uint_t bits = __float_as_uint(w);
        float hif = __uint_as_float(bits & 0xFFFF0000u);
        w2fh[layer * 4096 + t] = (ushort_t)(bits >> 16);
        w2fl[layer * 4096 + t] = f2bf(w - hif);
    }
}

// ---------------- layer-1 knn (C=1): bitonic sort + +/-16 window ----------------
__global__ __launch_bounds__(256) void knn1_sort_kernel(const float* __restrict__ pts,
                                                        int* __restrict__ idx_out) {
    __shared__ u64_t keys[NPTS];
    int b = blockIdx.x;
    int t = threadIdx.x;
    const float* base = pts + (size_t)b * NPTS;
    for (int s = t; s < NPTS; s += 256)
        keys[s] = ((u64_t)f2ord(base[s]) << 32) | (uint_t)s;
    for (int k = 2; k <= NPTS; k <<= 1) {
        for (int j2 = k >> 1; j2 > 0; j2 >>= 1) {
            __syncthreads();
            for (int i = t; i < NPTS; i += 256) {
                int ix = i ^ j2;
                if (ix > i) {
                    bool asc = ((i & k) == 0);
                    u64_t a = keys[i], c = keys[ix];
                    if ((a > c) == asc) { keys[i] = c; keys[ix] = a; }
                }
            }
        }
    }
    __syncthreads();
    for (int s = t; s < NPTS; s += 256) {
        u64_t me = keys[s];
        int jme = (int)(me & 0x3FFu);
        uint_t mo = (uint_t)(me >> 32);
        uint_t mu = (mo & 0x80000000u) ? (mo ^ 0x80000000u) : ~mo;
        float xs = __uint_as_float(mu);
        uint_t lst[KNB];
        #pragma unroll
        for (int k = 0; k < KNB; ++k) lst[k] = 0xFFFFFFFFu;
        int lo = s - 16; if (lo < 0) lo = 0;
        int hi = s + 16; if (hi > NPTS - 1) hi = NPTS - 1;
        for (int q = lo; q <= hi; ++q) {
            u64_t o = keys[q];
            uint_t oo = (uint_t)(o >> 32);
            uint_t ou = (oo & 0x80000000u) ? (oo ^ 0x80000000u) : ~oo;
            float xo = __uint_as_float(ou);
            float d = (xs - xo) * (xs - xo);
            insert16(lst, packdj(d, (int)(o & 0x3FFu)));
        }
        int* op = idx_out + ((size_t)b * NPTS + jme) * KNB;
        #pragma unroll
        for (int k = 0; k < KNB; ++k) op[k] = (int)(lst[k] & 0x3FFu);
    }
}

// ---------------- MFMA knn (C=64): 16x16x32 bf16 hi/lo, single top-16 list ----
// XCD swizzle: b = blockIdx & 63 keeps each batch on one XCD's L2.
__global__ __launch_bounds__(64, 4) void knn_mfma_kernel(const ushort_t* __restrict__ xh,
                                                         const ushort_t* __restrict__ xl,
                                                         const float* __restrict__ sq,
                                                         uint_t* __restrict__ cand) {
    constexpr int JC = NPTS / NCHUNK2;           // 256
    __shared__ uint_t dbuf[16 * 68];
    __shared__ float sqs[JC];
    int b     = blockIdx.x & 63;
    int rest  = blockIdx.x >> 6;                 // 0..63
    int ib    = rest >> 2;                       // 0..15
    int chunk = rest & 3;                        // 0..3
    int i0    = b * NPTS + ib * 64;
    int lane  = threadIdx.x;
    int m = lane & 15, quad = lane >> 4;
    int j0c = chunk * JC;

    for (int t = lane; t < JC; t += 64) sqs[t] = sq[b * NPTS + j0c + t];

    bf16x8_t Ah[4][2], Al[4][2];
    #pragma unroll
    for (int it = 0; it < 4; ++it) {
        #pragma unroll
        for (int kh = 0; kh < 2; ++kh) {
            size_t off = ((size_t)(i0 + it * 16 + m)) * 64 + kh * 32 + quad * 8;
            Ah[it][kh] = *(const bf16x8_t*)(xh + off);
            Al[it][kh] = *(const bf16x8_t*)(xl + off);
        }
    }
    float4 sqi[4];
    #pragma unroll
    for (int it = 0; it < 4; ++it)
        sqi[it] = *(const float4*)&sq[i0 + it * 16 + quad * 4];

    uint_t lst[KNB];
    #pragma unroll
    for (int k = 0; k < KNB; ++k) lst[k] = 0xFFFFFFFFu;
    __syncthreads();

    for (int g = 0; g < JC / 16; ++g) {
        int jg = j0c + g * 16;                       // batch-local j base
        size_t boff = ((size_t)(b * NPTS + jg + m)) * 64 + quad * 8;
        bf16x8_t Bh0 = *(const bf16x8_t*)(xh + boff);
        bf16x8_t Bh1 = *(const bf16x8_t*)(xh + boff + 32);
        bf16x8_t Bl0 = *(const bf16x8_t*)(xl + boff);
        bf16x8_t Bl1 = *(const bf16x8_t*)(xl + boff + 32);
        float sqj = sqs[g * 16 + m];
        int jm = jg + m;
        #pragma unroll
        for (int it = 0; it < 4; ++it) {
            f32x4_t acc = {0.f, 0.f, 0.f, 0.f};
            acc = __builtin_amdgcn_mfma_f32_16x16x32_bf16(Ah[it][0], Bh0, acc, 0, 0, 0);
            acc = __builtin_amdgcn_mfma_f32_16x16x32_bf16(Ah[it][1], Bh1, acc, 0, 0, 0);
            acc = __builtin_amdgcn_mfma_f32_16x16x32_bf16(Ah[it][0], Bl0, acc, 0, 0, 0);
            acc = __builtin_amdgcn_mfma_f32_16x16x32_bf16(Ah[it][1], Bl1, acc, 0, 0, 0);
            acc = __builtin_amdgcn_mfma_f32_16x16x32_bf16(Al[it][0], Bh0, acc, 0, 0, 0);
            acc = __builtin_amdgcn_mfma_f32_16x16x32_bf16(Al[it][1], Bh1, acc, 0, 0, 0);
            uint4 pv;
            pv.x = packdj(sqi[it].x + sqj - 2.0f * acc[0], jm);
            pv.y = packdj(sqi[it].y + sqj - 2.0f * acc[1], jm);
            pv.z = packdj(sqi[it].z + sqj - 2.0f * acc[2], jm);
            pv.w = packdj(sqi[it].w + sqj - 2.0f * acc[3], jm);
            *(uint4*)&dbuf[m * 68 + it * 16 + quad * 4] = pv;
        }
        __syncthreads();
        #pragma unroll
        for (int jj = 0; jj < 16; ++jj)
            insert16(lst, dbuf[jj * 68 + lane]);
        __syncthreads();
    }
    #pragma unroll
    for (int k = 0; k < KNB; ++k)
        cand[(size_t)(chunk * KNB + k) * NPOINTS + i0 + lane] = lst[k];
}

// ---------------- knn merge: NC packed candidates -> final top-16 indices ----------------
template<int NC>
__global__ __launch_bounds__(256) void knn_merge_kernel(const uint_t* __restrict__ cand,
                                                        int* __restrict__ idx_out) {
    int i = blockIdx.x * 256 + threadIdx.x;
    uint_t lst[KNB];
    #pragma unroll
    for (int k = 0; k < KNB; ++k) lst[k] = 0xFFFFFFFFu;
    #pragma unroll 4
    for (int t = 0; t < NC; ++t)
        insert16(lst, cand[(size_t)t * NPOINTS + i]);
    int* op = idx_out + (size_t)i * KNB;
    #pragma unroll
    for (int k = 0; k < KNB; ++k) op[k] = (int)(lst[k] & 0x3FFu);
}

// ---------------- uv for layer 1 (C_in = 1): elementwise ----------------
__global__ __launch_bounds__(256) void uv1_kernel(const float* __restrict__ x,
                                                  const float* __restrict__ w1,
                                                  const float* __restrict__ b1,
                                                  float* __restrict__ u,
                                                  float* __restrict__ v) {
    int lane = threadIdx.x & 63, wave = threadIdx.x >> 6;
    float wa = w1[lane], wb = w1[64 + lane], bb = b1[lane];
    float wd = wa - wb;
    int gw = blockIdx.x * 4 + wave;
    for (int p = gw; p < NPOINTS; p += 4096) {
        float xv = x[p];
        u[(size_t)p * 64 + lane] = fmaf(xv, wd, bb);
        v[(size_t)p * 64 + lane] = xv * wb;
    }
}

// ---------------- uv GEMM (CIN=64) ----------------
__global__ __launch_bounds__(256) void uv_gemm_kernel(const float* __restrict__ x,
                                                      const float* __restrict__ w1,
                                                      const float* __restrict__ b1,
                                                      float* __restrict__ u,
                                                      float* __restrict__ v) {
    __shared__ float As[64 * 68];
    __shared__ float Bs[64 * 128];
    int t = threadIdx.x;
    int p0 = blockIdx.x * 64;
    for (int g = t; g < 64 * 16; g += 256) {
        int c = g >> 4, o4 = (g & 15) * 4;
        float4 wa = *(const float4*)&w1[c * 64 + o4];
        float4 wb = *(const float4*)&w1[(64 + c) * 64 + o4];
        float4 d; d.x = wa.x - wb.x; d.y = wa.y - wb.y; d.z = wa.z - wb.z; d.w = wa.w - wb.w;
        *(float4*)&Bs[c * 128 + o4] = d;
    }
    for (int g = t; g < 64 * 16; g += 256) {
        int c = g >> 4, o4 = (g & 15) * 4;
        *(float4*)&Bs[c * 128 + 64 + o4] = *(const float4*)&w1[(64 + c) * 64 + o4];
    }
    {
        int pq = t >> 4, cq = t & 15;
        const float* xp = x + (size_t)(p0 + pq * 4) * 64 + cq * 4;
        float4 r0 = *(const float4*)&xp[0 * 64];
        float4 r1 = *(const float4*)&xp[1 * 64];
        float4 r2 = *(const float4*)&xp[2 * 64];
        float4 r3 = *(const float4*)&xp[3 * 64];
        float4 c0; c0.x = r0.x; c0.y = r1.x; c0.z = r2.x; c0.w = r3.x;
        float4 c1; c1.x = r0.y; c1.y = r1.y; c1.z = r2.y; c1.w = r3.y;
        float4 c2; c2.x = r0.z; c2.y = r1.z; c2.z = r2.z; c2.w = r3.z;
        float4 c3; c3.x = r0.w; c3.y = r1.w; c3.z = r2.w; c3.w = r3.w;
        *(float4*)&As[(cq * 4 + 0) * 68 + pq * 4] = c0;
        *(float4*)&As[(cq * 4 + 1) * 68 + pq * 4] = c1;
        *(float4*)&As[(cq * 4 + 2) * 68 + pq * 4] = c2;
        *(float4*)&As[(cq * 4 + 3) * 68 + pq * 4] = c3;
    }
    __syncthreads();
    int rg = t >> 4;
    int cg = t & 15;
    float acc[4][8];
    #pragma unroll
    for (int i = 0; i < 4; ++i)
        #pragma unroll
        for (int jj = 0; jj < 8; ++jj) acc[i][jj] = 0.f;
    #pragma unroll 4
    for (int c = 0; c < 64; ++c) {
        float4 a4 = *(const float4*)&As[c * 68 + rg * 4];
        float4 b0 = *(const float4*)&Bs[c * 128 + cg * 8];
        float4 b4 = *(const float4*)&Bs[c * 128 + cg * 8 + 4];
        float av[4] = {a4.x, a4.y, a4.z, a4.w};
        float bv[8] = {b0.x, b0.y, b0.z, b0.w, b4.x, b4.y, b4.z, b4.w};
        #pragma unroll
        for (int i = 0; i < 4; ++i)
            #pragma unroll
            for (int jj = 0; jj < 8; ++jj)
                acc[i][jj] = fmaf(av[i], bv[jj], acc[i][jj]);
    }
    if (cg < 8) {
        float4 bb0 = *(const float4*)&b1[cg * 8];
        float4 bb1 = *(const float4*)&b1[cg * 8 + 4];
        #pragma unroll
        for (int i = 0; i < 4; ++i) {
            size_t p = p0 + rg * 4 + i;
            float4 o0; o0.x = acc[i][0] + bb0.x; o0.y = acc[i][1] + bb0.y;
                       o0.z = acc[i][2] + bb0.z; o0.w = acc[i][3] + bb0.w;
            float4 o1; o1.x = acc[i][4] + bb1.x; o1.y = acc[i][5] + bb1.y;
                       o1.z = acc[i][6] + bb1.z; o1.w = acc[i][7] + bb1.w;
            *(float4*)&u[p * 64 + cg * 8]     = o0;
            *(float4*)&u[p * 64 + cg * 8 + 4] = o1;
        }
    } else {
        int o = (cg - 8) * 8;
        #pragma unroll
        for (int i = 0; i < 4; ++i) {
            size_t p = p0 + rg * 4 + i;
            float4 o0; o0.x = acc[i][0]; o0.y = acc[i][1]; o0.z = acc[i][2]; o0.w = acc[i][3];
            float4 o1; o1.x = acc[i][4]; o1.y = acc[i][5]; o1.z = acc[i][6]; o1.w = acc[i][7];
            *(float4*)&v[p * 64 + o]     = o0;
            *(float4*)&v[p * 64 + o + 4] = o1;
        }
    }
}

// ---------------- edge MFMA: wave = 1 point/step, A=relu(u+v) hi/lo, prefab w2 frags ----
// XCD swizzle: b = blockIdx & 63 -> all 64 blocks of a batch land on one XCD
// (same fix that collapsed knn_mfma's FETCH in R12); the v-gather then hits
// that XCD's L2 (8 batches x 512 KB u+v = 4 MB).
template<bool WF32, bool WSQ>
__global__ __launch_bounds__(256) void edge_mfma_kernel(const float* __restrict__ u,
                                                        const float* __restrict__ v,
                                                        const int* __restrict__ idx,
                                                        const ushort_t* __restrict__ w2fh,
                                                        const ushort_t* __restrict__ w2fl,
                                                        const float* __restrict__ b2,
                                                        float* __restrict__ out,
                                                        ushort_t* __restrict__ oh,
                                                        ushort_t* __restrict__ ol,
                                                        float* __restrict__ sqout) {
    int wave = threadIdx.x >> 6, lane = threadIdx.x & 63;
    int m = lane & 15, quad = lane >> 4;
    bf16x8_t Bh[4][2], Bl[4][2];
    #pragma unroll
    for (int ct = 0; ct < 4; ++ct) {
        #pragma unroll
        for (int kh = 0; kh < 2; ++kh) {
            size_t boff = (size_t)((ct * 2 + kh) * 64 + lane) * 8;
            Bh[ct][kh] = *(const bf16x8_t*)(w2fh + boff);
            Bl[ct][kh] = *(const bf16x8_t*)(w2fl + boff);
        }
    }
    float bias[4];
    #pragma unroll
    for (int ct = 0; ct < 4; ++ct) bias[ct] = b2[ct * 16 + m];
    int bb_ = blockIdx.x & 63;                  // batch (XCD-pinned)
    int r_  = blockIdx.x >> 6;                  // 0..63 within batch
    int p0 = bb_ * NPTS + r_ * 16 + wave * 4;
    int jv[4];
    #pragma unroll
    for (int pi = 0; pi < 4; ++pi) jv[pi] = idx[(p0 + pi) * 16 + m];
    #pragma unroll
    for (int pi = 0; pi < 4; ++pi) {
        int p = p0 + pi;
        const float* up = u + (size_t)p * 64;
        const float* vp = v + ((size_t)(bb_ << 10) + jv[pi]) * 64;
        bf16x8_t Ah[2], Al[2];
        #pragma unroll
        for (int kh = 0; kh < 2; ++kh) {
            int c0 = kh * 32 + quad * 8;
            float4 ua = *(const float4*)(up + c0);
            float4 ub = *(const float4*)(up + c0 + 4);
            float4 va = *(const float4*)(vp + c0);
            float4 vb = *(const float4*)(vp + c0 + 4);
            float f[8] = {ua.x + va.x, ua.y + va.y, ua.z + va.z, ua.w + va.w,
                          ub.x + vb.x, ub.y + vb.y, ub.z + vb.z, ub.w + vb.w};
            union { ushort_t s[8]; bf16x8_t v8; } H, L;
            #pragma unroll
            for (int e = 0; e < 8; ++e) {
                float g = fmaxf(f[e], 0.f);
                uint_t bits = __float_as_uint(g);
                H.s[e] = (ushort_t)(bits >> 16);
                float hif = __uint_as_float(bits & 0xFFFF0000u);
                L.s[e] = (ushort_t)(__float_as_uint(g - hif) >> 16);
            }
            Ah[kh] = H.v8; Al[kh] = L.v8;
        }
        float val[4];
        #pragma unroll
        for (int ct = 0; ct < 4; ++ct) {
            f32x4_t acc = {0.f, 0.f, 0.f, 0.f};
            acc = __builtin_amdgcn_mfma_f32_16x16x32_bf16(Ah[0], Bh[ct][0], acc, 0, 0, 0);
            acc = __builtin_amdgcn_mfma_f32_16x16x32_bf16(Ah[1], Bh[ct][1], acc, 0, 0, 0);
            acc = __builtin_amdgcn_mfma_f32_16x16x32_bf16(Ah[0], Bl[ct][0], acc, 0, 0, 0);
            acc = __builtin_amdgcn_mfma_f32_16x16x32_bf16(Ah[1], Bl[ct][1], acc, 0, 0, 0);
            acc = __builtin_amdgcn_mfma_f32_16x16x32_bf16(Al[0], Bh[ct][0], acc, 0, 0, 0);
            acc = __builtin_amdgcn_mfma_f32_16x16x32_bf16(Al[1], Bh[ct][1], acc, 0, 0, 0);
            float mm = fmaxf(fmaxf(acc[0], acc[1]), fmaxf(acc[2], acc[3]));
            mm = fmaxf(mm, __shfl_xor(mm, 16, 64));
            mm = fmaxf(mm, __shfl_xor(mm, 32, 64));   // mm now quad-uniform
            val[ct] = mm + bias[ct];
        }
        if constexpr (WSQ) {
            float partial = val[0] * val[0] + val[1] * val[1]
                          + val[2] * val[2] + val[3] * val[3];
            partial += __shfl_xor(partial, 1, 64);
            partial += __shfl_xor(partial, 2, 64);
            partial += __shfl_xor(partial, 4, 64);
            partial += __shfl_xor(partial, 8, 64);
            if (lane == 0) sqout[p] = partial;
        }
        if (quad == 0) {
            #pragma unroll
            for (int ct = 0; ct < 4; ++ct) {
                int o = ct * 16 + m;
                float vv = val[ct];
                if constexpr (WF32) out[(size_t)p * 64 + o] = vv;
                uint_t bits = __float_as_uint(vv);
                oh[(size_t)p * 64 + o] = (ushort_t)(bits >> 16);
                float hif = __uint_as_float(bits & 0xFFFF0000u);
                ol[(size_t)p * 64 + o] = f2bf(vv - hif);
            }
        }
    }
}

// ---------------- final MLP: wave-private, barrier-free (converged structure) ----------------
__global__ __launch_bounds__(128, 2) void mlp_kernel(const ushort_t* __restrict__ xh1,
                                                  const ushort_t* __restrict__ xl1,
                                                  const ushort_t* __restrict__ xh2,
                                                  const ushort_t* __restrict__ xl2,
                                                  const ushort_t* __restrict__ xh3,
                                                  const ushort_t* __restrict__ xl3,
                                                  const ushort_t* __restrict__ w1fh,
                                                  const ushort_t* __restrict__ w1fl,
                                                  const float* __restrict__ mb1,
                                                  const float* __restrict__ mw2, const float* __restrict__ mb2,
                                                  const float* __restrict__ mw3, const float* __restrict__ mb3,
                                                  const float* __restrict__ mw4, const float* __restrict__ mb4,
                                                  float* __restrict__ out) {
    __shared__ float smem[2][128 * 17];      // 8704 B per wave
    int wave = threadIdx.x >> 6, lane = threadIdx.x & 63;
    float* h1w = smem[wave];                 // [128][17]
    float* h2w = smem[wave];                 // [64][17]  overlays h1 (written after all h1 reads)
    float* h3w = smem[wave] + 64 * 17;       // [32][17]  overlays h1's upper half
    int m = lane & 15, quad = lane >> 4;
    int pw = blockIdx.x * 32 + wave * 16;    // this wave's 16 points

    const ushort_t* HS[3] = {xh1, xh2, xh3};
    const ushort_t* LS[3] = {xl1, xl2, xl3};
    bf16x8_t Ah[6], Al[6];
    #pragma unroll
    for (int ks = 0; ks < 6; ++ks) {
        size_t aoff = (size_t)(pw + m) * 64 + (ks & 1) * 32 + quad * 8;
        Ah[ks] = *(const bf16x8_t*)(HS[ks >> 1] + aoff);
        Al[ks] = *(const bf16x8_t*)(LS[ks >> 1] + aoff);
    }
    f32x4_t acc1[8];
    #pragma unroll
    for (int nt = 0; nt < 8; ++nt) acc1[nt] = (f32x4_t){0.f, 0.f, 0.f, 0.f};
    #pragma unroll
    for (int ks = 0; ks < 6; ++ks) {
        bf16x8_t Bh[8], Bl[8];
        #pragma unroll
        for (int nt = 0; nt < 8; ++nt) {
            size_t boff = (size_t)(nt * 6 + ks) * 512 + lane * 8;
            Bh[nt] = *(const bf16x8_t*)(w1fh + boff);
            Bl[nt] = *(const bf16x8_t*)(w1fl + boff);
        }
        #pragma unroll
        for (int nt = 0; nt < 8; ++nt) {
            acc1[nt] = __builtin_amdgcn_mfma_f32_16x16x32_bf16(Ah[ks], Bh[nt], acc1[nt], 0, 0, 0);
            acc1[nt] = __builtin_amdgcn_mfma_f32_16x16x32_bf16(Ah[ks], Bl[nt], acc1[nt], 0, 0, 0);
            acc1[nt] = __builtin_amdgcn_mfma_f32_16x16x32_bf16(Al[ks], Bh[nt], acc1[nt], 0, 0, 0);
        }
    }
    #pragma unroll
    for (int nt = 0; nt < 8; ++nt) {
        float bb = mb1[nt * 16 + m];
        float4 w;
        w.x = fmaxf(acc1[nt][0] + bb, 0.f);
        w.y = fmaxf(acc1[nt][1] + bb, 0.f);
        w.z = fmaxf(acc1[nt][2] + bb, 0.f);
        w.w = fmaxf(acc1[nt][3] + bb, 0.f);
        *(float4*)&h1w[(nt * 16 + m) * 17 + quad * 4] = w;
    }
    float acc2[4][4];
    {
        float4 bb = *(const float4*)&mb2[m * 4];
        #pragma unroll
        for (int i = 0; i < 4; ++i) {
            acc2[i][0] = bb.x; acc2[i][1] = bb.y; acc2[i][2] = bb.z; acc2[i][3] = bb.w;
        }
    }
    for (int cc = 0; cc < 128; cc += 8) {
        float4 wv[8], av4[8];
        #pragma unroll
        for (int q = 0; q < 8; ++q) wv[q] = *(const float4*)&mw2[(cc + q) * 64 + m * 4];
        #pragma unroll
        for (int q = 0; q < 8; ++q) av4[q] = *(const float4*)&h1w[(cc + q) * 17 + quad * 4];
        #pragma unroll
        for (int q = 0; q < 8; ++q) {
            float av[4] = {av4[q].x, av4[q].y, av4[q].z, av4[q].w};
            float bv[4] = {wv[q].x, wv[q].y, wv[q].z, wv[q].w};
            #pragma unroll
            for (int i = 0; i < 4; ++i)
                #pragma unroll
                for (int jj = 0; jj < 4; ++jj)
                    acc2[i][jj] = fmaf(av[i], bv[jj], acc2[i][jj]);
        }
    }
    #pragma unroll
    for (int jj = 0; jj < 4; ++jj) {
        float4 w;
        w.x = fmaxf(acc2[0][jj], 0.f); w.y = fmaxf(acc2[1][jj], 0.f);
        w.z = fmaxf(acc2[2][jj], 0.f); w.w = fmaxf(acc2[3][jj], 0.f);
        *(float4*)&h2w[(m * 4 + jj) * 17 + quad * 4] = w;
    }
    float acc3[4][2];
    {
        float2 bb = *(const float2*)&mb3[m * 2];
        #pragma unroll
        for (int i = 0; i < 4; ++i) { acc3[i][0] = bb.x; acc3[i][1] = bb.y; }
    }
    for (int cc = 0; cc < 64; cc += 8) {
        float2 wv[8]; float4 av4[8];
        #pragma unroll
        for (int q = 0; q < 8; ++q) wv[q] = *(const float2*)&mw3[(cc + q) * 32 + m * 2];
        #pragma unroll
        for (int q = 0; q < 8; ++q) av4[q] = *(const float4*)&h2w[(cc + q) * 17 + quad * 4];
        #pragma unroll
        for (int q = 0; q < 8; ++q) {
            float av[4] = {av4[q].x, av4[q].y, av4[q].z, av4[q].w};
            #pragma unroll
            for (int i = 0; i < 4; ++i) {
                acc3[i][0] = fmaf(av[i], wv[q].x, acc3[i][0]);
                acc3[i][1] = fmaf(av[i], wv[q].y, acc3[i][1]);
            }
        }
    }
    #pragma unroll
    for (int jj = 0; jj < 2; ++jj) {
        float4 w;
        w.x = fmaxf(acc3[0][jj], 0.f); w.y = fmaxf(acc3[1][jj], 0.f);
        w.z = fmaxf(acc3[2][jj], 0.f); w.w = fmaxf(acc3[3][jj], 0.f);
        *(float4*)&h3w[(m * 2 + jj) * 17 + quad * 4] = w;
    }
    if (lane < 16) {
        float z0 = mb4[0], z1 = mb4[1];
        #pragma unroll 8
        for (int c = 0; c < 32; ++c) {
            float h = h3w[c * 17 + lane];
            z0 = fmaf(h, mw4[c * 2 + 0], z0);
            z1 = fmaf(h, mw4[c * 2 + 1], z1);
        }
        float mx = fmaxf(z0, z1);
        float ls = mx + logf(expf(z0 - mx) + expf(z1 - mx));
        float2 o; o.x = z0 - ls; o.y = z1 - ls;
        *(float2*)&out[(size_t)(pw + lane) * 2] = o;
    }
}

extern "C" void kernel_launch(void* const* d_in, const int* in_sizes, int n_in,
                              void* d_out, int out_size, void* d_ws, size_t ws_size,
                              hipStream_t stream) {
    const float* x0   = (const float*)d_in[0];
    const float* c1w1 = (const float*)d_in[1];  const float* c1b1 = (const float*)d_in[2];
    const float* c1w2 = (const float*)d_in[3];  const float* c1b2 = (const float*)d_in[4];
    const float* c2w1 = (const float*)d_in[5];  const float* c2b1 = (const float*)d_in[6];
    const float* c2w2 = (const float*)d_in[7];  const float* c2b2 = (const float*)d_in[8];
    const float* c3w1 = (const float*)d_in[9];  const float* c3b1 = (const float*)d_in[10];
    const float* c3w2 = (const float*)d_in[11]; const float* c3b2 = (const float*)d_in[12];
    const float* mw1  = (const float*)d_in[13]; const float* mb1  = (const float*)d_in[14];
    const float* mw2  = (const float*)d_in[15]; const float* mb2  = (const float*)d_in[16];
    const float* mw3  = (const float*)d_in[17]; const float* mb3  = (const float*)d_in[18];
    const float* mw4  = (const float*)d_in[19]; const float* mb4  = (const float*)d_in[20];

    float* ws = (float*)d_ws;
    const size_t NF = (size_t)NPOINTS * 64;
    float* x1 = ws;                      // fp32 (uv L2 input)
    float* x2 = x1 + NF;                 // fp32 (uv L3 input)
    ushort_t* xh3 = (ushort_t*)(x2 + NF);
    ushort_t* xl3 = xh3 + NF;
    float* u  = (float*)(xl3 + NF);
    float* v  = u + NF;
    float* sq = v + NF;
    int*  idx = (int*)(sq + NPOINTS);
    ushort_t* xh1 = (ushort_t*)(idx + (size_t)NPOINTS * KNB);
    ushort_t* xl1 = xh1 + NF;
    ushort_t* xh2 = xl1 + NF;
    ushort_t* xl2 = xh2 + NF;
    ushort_t* w1fh = xl2 + NF;
    ushort_t* w1fl = w1fh + 128 * 192;
    ushort_t* w2fh = w1fl + 128 * 192;   // 3 layers x 4096
    ushort_t* w2fl = w2fh + 3 * 4096;
    uint_t* cand = (uint_t*)u;     // aliases u..v (64 slots x NPOINTS = 16 MB)
    float* out = (float*)d_out;

    // ---- fused weight prep ----
    prep_kernel<<<144, 256, 0, stream>>>(mw1, c1w2, c2w2, c3w2,
                                         w1fh, w1fl, w2fh, w2fl);
    // ---- layer 1 (C_in = 1): sort-window knn ----
    knn1_sort_kernel<<<NB, 256, 0, stream>>>(x0, idx);
    uv1_kernel<<<1024, 256, 0, stream>>>(x0, c1w1, c1b1, u, v);
    edge_mfma_kernel<true, true><<<NPOINTS / 16, 256, 0, stream>>>(
        u, v, idx, w2fh, w2fl, c1b2, x1, xh1, xl1, sq);
    // ---- layer 2: MFMA knn on xh1/xl1 (sq fused in edge L1) ----
    knn_mfma_kernel<<<NB * 16 * NCHUNK2, 64, 0, stream>>>(xh1, xl1, sq, cand);
    knn_merge_kernel<NCHUNK2 * KNB><<<NPOINTS / 256, 256, 0, stream>>>(cand, idx);
    uv_gemm_kernel<<<NPOINTS / 64, 256, 0, stream>>>(x1, c2w1, c2b1, u, v);
    edge_mfma_kernel<true, true><<<NPOINTS / 16, 256, 0, stream>>>(
        u, v, idx, w2fh + 4096, w2fl + 4096, c2b2, x2, xh2, xl2, sq);
    // ---- layer 3: MFMA knn on xh2/xl2 (sq fused in edge L2) ----
    knn_mfma_kernel<<<NB * 16 * NCHUNK2, 64, 0, stream>>>(xh2, xl2, sq, cand);
    knn_merge_kernel<NCHUNK2 * KNB><<<NPOINTS / 256, 256, 0, stream>>>(cand, idx);
    uv_gemm_kernel<<<NPOINTS / 64, 256, 0, stream>>>(x2, c3w1, c3b1, u, v);
    edge_mfma_kernel<false, false><<<NPOINTS / 16, 256, 0, stream>>>(
        u, v, idx, w2fh + 8192, w2fl + 8192, c3b2, nullptr, xh3, xl3, nullptr);
    // ---- final MLP + log_softmax ----
    mlp_kernel<<<NPOINTS / 32, 128, 0, stream>>>(xh1, xl1, xh2, xl2, xh3, xl3,
                                                 w1fh, w1fl, mb1, mw2, mb2,
                                                 mw3, mb3, mw4, mb4, out);
}

// Round 17
// 574.567 us; speedup vs baseline: 1.0335x; 1.0335x over previous
//
#include <hip/hip_runtime.h>
#include <math.h>

typedef unsigned short ushort_t;
typedef unsigned int uint_t;
typedef unsigned long long u64_t;
typedef __bf16 bf16x8_t __attribute__((ext_vector_type(8)));
typedef float f32x4_t __attribute__((ext_vector_type(4)));

static constexpr int NPTS = 1024;
static constexpr int NB = 64;
static constexpr int NPOINTS = NB * NPTS;   // 65536
static constexpr int KNB = 16;

__device__ __forceinline__ ushort_t f2bf(float f) {
    uint_t u = __float_as_uint(f);
    uint_t r = (u + 0x7FFFu + ((u >> 16) & 1u)) >> 16;
    return (ushort_t)r;
}
// pack distance (clamped >=0, 22 bits kept) + batch-local j (10 bits).
__device__ __forceinline__ uint_t packdj(float d, int j) {
    return (__float_as_uint(fmaxf(d, 0.f)) & 0xFFFFFC00u) | (uint_t)j;
}
// single-instruction median: for sorted L[k-1]<=L[k], post-insert
// L'[k] = med3(L[k-1], L[k], c). One VOP3 per step; all steps independent.
__device__ __forceinline__ uint_t med3u(uint_t a, uint_t b, uint_t c) {
    uint_t d;
    asm("v_med3_u32 %0, %1, %2, %3" : "=v"(d) : "v"(a), "v"(b), "v"(c));
    return d;
}
__device__ __forceinline__ void insert16(uint_t* L, uint_t c) {
    #pragma unroll
    for (int k = 15; k > 0; --k)
        L[k] = med3u(L[k - 1], L[k], c);
    L[0] = L[0] < c ? L[0] : c;
}
// monotone float->uint order transform
__device__ __forceinline__ uint_t f2ord(float f) {
    uint_t u = __float_as_uint(f);
    return (u & 0x80000000u) ? ~u : (u ^ 0x80000000u);
}

// ---------------- fused weight prep: w1 (frag-contig) + 3x w2 (frag-contig) ----------------
__global__ __launch_bounds__(256) void prep_kernel(const float* __restrict__ mw1,
                                                   const float* __restrict__ c1w2,
                                                   const float* __restrict__ c2w2,
                                                   const float* __restrict__ c3w2,
                                                   ushort_t* __restrict__ w1fh,
                                                   ushort_t* __restrict__ w1fl,
                                                   ushort_t* __restrict__ w2fh,  // 3 layers concat
                                                   ushort_t* __restrict__ w2fl) {
    int blk = blockIdx.x;
    if (blk < 96) {
        int t = blk * 256 + threadIdx.x;         // 0..24575
        int e = t & 7;
        int lane = (t >> 3) & 63;
        int fs = t >> 9;                         // frag id = nt*6+ks, 0..47
        int nt = fs / 6, ks = fs - nt * 6;
        int m = lane & 15, quad = lane >> 4;
        int k = ks * 32 + quad * 8 + e;
        int n = nt * 16 + m;
        float w = mw1[k * 128 + n];
        uint_t bits = __float_as_uint(w);
        float hif = __uint_as_float(bits & 0xFFFF0000u);
        w1fh[t] = (ushort_t)(bits >> 16);
        w1fl[t] = f2bf(w - hif);
    } else {
        int layer = (blk - 96) >> 4;             // 0..2
        const float* w2 = layer == 0 ? c1w2 : (layer == 1 ? c2w2 : c3w2);
        int t = ((blk - 96) & 15) * 256 + threadIdx.x;   // 0..4095
        int e = t & 7;
        int lane = (t >> 3) & 63;
        int fs = t >> 9;                         // frag id = ct*2+kh, 0..7
        int ct = fs >> 1, kh = fs & 1;
        int m = lane & 15, quad = lane >> 4;
        int k = kh * 32 + quad * 8 + e;
        int n = ct * 16 + m;
        float w = w2[k * 64 + n];
        uint_t bits = __float_as_uint(w);
        float hif = __uint_as_float(bits & 0xFFFF0000u);
        w2fh[layer * 4096 + t] = (ushort_t)(bits >> 16);
        w2fl[layer * 4096 + t] = f2bf(w - hif);
    }
}

// ---------------- layer-1 knn (C=1): bitonic sort + +/-16 window ----------------
__global__ __launch_bounds__(256) void knn1_sort_kernel(const float* __restrict__ pts,
                                                        int* __restrict__ idx_out) {
    __shared__ u64_t keys[NPTS];
    int b = blockIdx.x;
    int t = threadIdx.x;
    const float* base = pts + (size_t)b * NPTS;
    for (int s = t; s < NPTS; s += 256)
        keys[s] = ((u64_t)f2ord(base[s]) << 32) | (uint_t)s;
    for (int k = 2; k <= NPTS; k <<= 1) {
        for (int j2 = k >> 1; j2 > 0; j2 >>= 1) {
            __syncthreads();
            for (int i = t; i < NPTS; i += 256) {
                int ix = i ^ j2;
                if (ix > i) {
                    bool asc = ((i & k) == 0);
                    u64_t a = keys[i], c = keys[ix];
                    if ((a > c) == asc) { keys[i] = c; keys[ix] = a; }
                }
            }
        }
    }
    __syncthreads();
    for (int s = t; s < NPTS; s += 256) {
        u64_t me = keys[s];
        int jme = (int)(me & 0x3FFu);
        uint_t mo = (uint_t)(me >> 32);
        uint_t mu = (mo & 0x80000000u) ? (mo ^ 0x80000000u) : ~mo;
        float xs = __uint_as_float(mu);
        uint_t lst[KNB];
        #pragma unroll
        for (int k = 0; k < KNB; ++k) lst[k] = 0xFFFFFFFFu;
        int lo = s - 16; if (lo < 0) lo = 0;
        int hi = s + 16; if (hi > NPTS - 1) hi = NPTS - 1;
        for (int q = lo; q <= hi; ++q) {
            u64_t o = keys[q];
            uint_t oo = (uint_t)(o >> 32);
            uint_t ou = (oo & 0x80000000u) ? (oo ^ 0x80000000u) : ~oo;
            float xo = __uint_as_float(ou);
            float d = (xs - xo) * (xs - xo);
            insert16(lst, packdj(d, (int)(o & 0x3FFu)));
        }
        int* op = idx_out + ((size_t)b * NPTS + jme) * KNB;
        #pragma unroll
        for (int k = 0; k < KNB; ++k) op[k] = (int)(lst[k] & 0x3FFu);
    }
}

// ---------------- MFMA knn (C=64), FUSED: block = (batch, i-block), wave = chunk ----
// 4 waves each scan one 256-j chunk with wave-private dbuf/sqs (no barriers in
// the main loop); one __syncthreads; wave 0 merges 4x16 per lane and writes idx
// directly -- eliminates the 16 MB cand round-trip + the merge kernel.
// XCD swizzle: b = blockIdx & 63 keeps each batch on one XCD's L2.
__global__ __launch_bounds__(256, 4) void knn_mfma_kernel(const ushort_t* __restrict__ xh,
                                                          const ushort_t* __restrict__ xl,
                                                          const float* __restrict__ sq,
                                                          int* __restrict__ idx_out) {
    constexpr int JC = NPTS / 4;                 // 256 j per chunk(=wave)
    __shared__ uint_t dbuf[4][16 * 68];
    __shared__ float sqs[4][JC];
    __shared__ uint_t mlst[4][64][17];           // [chunk][i-lane][k], stride-17
    int b    = blockIdx.x & 63;
    int ib   = blockIdx.x >> 6;                  // 0..15
    int wave = threadIdx.x >> 6;                 // = chunk
    int lane = threadIdx.x & 63;
    int i0   = b * NPTS + ib * 64;
    int m = lane & 15, quad = lane >> 4;
    int j0c = wave * JC;

    for (int t = lane; t < JC; t += 64) sqs[wave][t] = sq[b * NPTS + j0c + t];

    bf16x8_t Ah[4][2], Al[4][2];
    #pragma unroll
    for (int it = 0; it < 4; ++it) {
        #pragma unroll
        for (int kh = 0; kh < 2; ++kh) {
            size_t off = ((size_t)(i0 + it * 16 + m)) * 64 + kh * 32 + quad * 8;
            Ah[it][kh] = *(const bf16x8_t*)(xh + off);
            Al[it][kh] = *(const bf16x8_t*)(xl + off);
        }
    }
    float4 sqi[4];
    #pragma unroll
    for (int it = 0; it < 4; ++it)
        sqi[it] = *(const float4*)&sq[i0 + it * 16 + quad * 4];

    uint_t lst[KNB];
    #pragma unroll
    for (int k = 0; k < KNB; ++k) lst[k] = 0xFFFFFFFFu;

    for (int g = 0; g < JC / 16; ++g) {
        int jg = j0c + g * 16;                       // batch-local j base
        size_t boff = ((size_t)(b * NPTS + jg + m)) * 64 + quad * 8;
        bf16x8_t Bh0 = *(const bf16x8_t*)(xh + boff);
        bf16x8_t Bh1 = *(const bf16x8_t*)(xh + boff + 32);
        bf16x8_t Bl0 = *(const bf16x8_t*)(xl + boff);
        bf16x8_t Bl1 = *(const bf16x8_t*)(xl + boff + 32);
        float sqj = sqs[wave][g * 16 + m];
        int jm = jg + m;
        #pragma unroll
        for (int it = 0; it < 4; ++it) {
            f32x4_t acc = {0.f, 0.f, 0.f, 0.f};
            acc = __builtin_amdgcn_mfma_f32_16x16x32_bf16(Ah[it][0], Bh0, acc, 0, 0, 0);
            acc = __builtin_amdgcn_mfma_f32_16x16x32_bf16(Ah[it][1], Bh1, acc, 0, 0, 0);
            acc = __builtin_amdgcn_mfma_f32_16x16x32_bf16(Ah[it][0], Bl0, acc, 0, 0, 0);
            acc = __builtin_amdgcn_mfma_f32_16x16x32_bf16(Ah[it][1], Bl1, acc, 0, 0, 0);
            acc = __builtin_amdgcn_mfma_f32_16x16x32_bf16(Al[it][0], Bh0, acc, 0, 0, 0);
            acc = __builtin_amdgcn_mfma_f32_16x16x32_bf16(Al[it][1], Bh1, acc, 0, 0, 0);
            uint4 pv;
            pv.x = packdj(sqi[it].x + sqj - 2.0f * acc[0], jm);
            pv.y = packdj(sqi[it].y + sqj - 2.0f * acc[1], jm);
            pv.z = packdj(sqi[it].z + sqj - 2.0f * acc[2], jm);
            pv.w = packdj(sqi[it].w + sqj - 2.0f * acc[3], jm);
            *(uint4*)&dbuf[wave][m * 68 + it * 16 + quad * 4] = pv;
        }
        // dbuf is wave-private: ds-ordering within the wave, no barrier.
        #pragma unroll
        for (int jj = 0; jj < 16; ++jj)
            insert16(lst, dbuf[wave][jj * 68 + lane]);
    }
    #pragma unroll
    for (int k = 0; k < KNB; ++k) mlst[wave][lane][k] = lst[k];
    __syncthreads();
    if (wave == 0) {
        uint_t fin[KNB];
        #pragma unroll
        for (int k = 0; k < KNB; ++k) fin[k] = 0xFFFFFFFFu;
        #pragma unroll
        for (int c = 0; c < 4; ++c)
            #pragma unroll
            for (int k = 0; k < KNB; ++k)
                insert16(fin, mlst[c][lane][k]);
        int* op = idx_out + (size_t)(i0 + lane) * KNB;
        #pragma unroll
        for (int k = 0; k < KNB; ++k) op[k] = (int)(fin[k] & 0x3FFu);
    }
}

// ---------------- uv for layer 1 (C_in = 1): elementwise ----------------
__global__ __launch_bounds__(256) void uv1_kernel(const float* __restrict__ x,
                                                  const float* __restrict__ w1,
                                                  const float* __restrict__ b1,
                                                  float* __restrict__ u,
                                                  float* __restrict__ v) {
    int lane = threadIdx.x & 63, wave = threadIdx.x >> 6;
    float wa = w1[lane], wb = w1[64 + lane], bb = b1[lane];
    float wd = wa - wb;
    int gw = blockIdx.x * 4 + wave;
    for (int p = gw; p < NPOINTS; p += 4096) {
        float xv = x[p];
        u[(size_t)p * 64 + lane] = fmaf(xv, wd, bb);
        v[(size_t)p * 64 + lane] = xv * wb;
    }
}

// ---------------- uv GEMM (CIN=64) ----------------
__global__ __launch_bounds__(256) void uv_gemm_kernel(const float* __restrict__ x,
                                                      const float* __restrict__ w1,
                                                      const float* __restrict__ b1,
                                                      float* __restrict__ u,
                                                      float* __restrict__ v) {
    __shared__ float As[64 * 68];
    __shared__ float Bs[64 * 128];
    int t = threadIdx.x;
    int p0 = blockIdx.x * 64;
    for (int g = t; g < 64 * 16; g += 256) {
        int c = g >> 4, o4 = (g & 15) * 4;
        float4 wa = *(const float4*)&w1[c * 64 + o4];
        float4 wb = *(const float4*)&w1[(64 + c) * 64 + o4];
        float4 d; d.x = wa.x - wb.x; d.y = wa.y - wb.y; d.z = wa.z - wb.z; d.w = wa.w - wb.w;
        *(float4*)&Bs[c * 128 + o4] = d;
    }
    for (int g = t; g < 64 * 16; g += 256) {
        int c = g >> 4, o4 = (g & 15) * 4;
        *(float4*)&Bs[c * 128 + 64 + o4] = *(const float4*)&w1[(64 + c) * 64 + o4];
    }
    {
        int pq = t >> 4, cq = t & 15;
        const float* xp = x + (size_t)(p0 + pq * 4) * 64 + cq * 4;
        float4 r0 = *(const float4*)&xp[0 * 64];
        float4 r1 = *(const float4*)&xp[1 * 64];
        float4 r2 = *(const float4*)&xp[2 * 64];
        float4 r3 = *(const float4*)&xp[3 * 64];
        float4 c0; c0.x = r0.x; c0.y = r1.x; c0.z = r2.x; c0.w = r3.x;
        float4 c1; c1.x = r0.y; c1.y = r1.y; c1.z = r2.y; c1.w = r3.y;
        float4 c2; c2.x = r0.z; c2.y = r1.z; c2.z = r2.z; c2.w = r3.z;
        float4 c3; c3.x = r0.w; c3.y = r1.w; c3.z = r2.w; c3.w = r3.w;
        *(float4*)&As[(cq * 4 + 0) * 68 + pq * 4] = c0;
        *(float4*)&As[(cq * 4 + 1) * 68 + pq * 4] = c1;
        *(float4*)&As[(cq * 4 + 2) * 68 + pq * 4] = c2;
        *(float4*)&As[(cq * 4 + 3) * 68 + pq * 4] = c3;
    }
    __syncthreads();
    int rg = t >> 4;
    int cg = t & 15;
    float acc[4][8];
    #pragma unroll
    for (int i = 0; i < 4; ++i)
        #pragma unroll
        for (int jj = 0; jj < 8; ++jj) acc[i][jj] = 0.f;
    #pragma unroll 4
    for (int c = 0; c < 64; ++c) {
        float4 a4 = *(const float4*)&As[c * 68 + rg * 4];
        float4 b0 = *(const float4*)&Bs[c * 128 + cg * 8];
        float4 b4 = *(const float4*)&Bs[c * 128 + cg * 8 + 4];
        float av[4] = {a4.x, a4.y, a4.z, a4.w};
        float bv[8] = {b0.x, b0.y, b0.z, b0.w, b4.x, b4.y, b4.z, b4.w};
        #pragma unroll
        for (int i = 0; i < 4; ++i)
            #pragma unroll
            for (int jj = 0; jj < 8; ++jj)
                acc[i][jj] = fmaf(av[i], bv[jj], acc[i][jj]);
    }
    if (cg < 8) {
        float4 bb0 = *(const float4*)&b1[cg * 8];
        float4 bb1 = *(const float4*)&b1[cg * 8 + 4];
        #pragma unroll
        for (int i = 0; i < 4; ++i) {
            size_t p = p0 + rg * 4 + i;
            float4 o0; o0.x = acc[i][0] + bb0.x; o0.y = acc[i][1] + bb0.y;
                       o0.z = acc[i][2] + bb0.z; o0.w = acc[i][3] + bb0.w;
            float4 o1; o1.x = acc[i][4] + bb1.x; o1.y = acc[i][5] + bb1.y;
                       o1.z = acc[i][6] + bb1.z; o1.w = acc[i][7] + bb1.w;
            *(float4*)&u[p * 64 + cg * 8]     = o0;
            *(float4*)&u[p * 64 + cg * 8 + 4] = o1;
        }
    } else {
        int o = (cg - 8) * 8;
        #pragma unroll
        for (int i = 0; i < 4; ++i) {
            size_t p = p0 + rg * 4 + i;
            float4 o0; o0.x = acc[i][0]; o0.y = acc[i][1]; o0.z = acc[i][2]; o0.w = acc[i][3];
            float4 o1; o1.x = acc[i][4]; o1.y = acc[i][5]; o1.z = acc[i][6]; o1.w = acc[i][7];
            *(float4*)&v[p * 64 + o]     = o0;
            *(float4*)&v[p * 64 + o + 4] = o1;
        }
    }
}

// ---------------- edge MFMA: wave = 1 point/step, A=relu(u+v) hi/lo, prefab w2 frags ----
template<bool WF32, bool WSQ>
__global__ __launch_bounds__(256) void edge_mfma_kernel(const float* __restrict__ u,
                                                        const float* __restrict__ v,
                                                        const int* __restrict__ idx,
                                                        const ushort_t* __restrict__ w2fh,
                                                        const ushort_t* __restrict__ w2fl,
                                                        const float* __restrict__ b2,
                                                        float* __restrict__ out,
                                                        ushort_t* __restrict__ oh,
                                                        ushort_t* __restrict__ ol,
                                                        float* __restrict__ sqout) {
    int wave = threadIdx.x >> 6, lane = threadIdx.x & 63;
    int m = lane & 15, quad = lane >> 4;
    bf16x8_t Bh[4][2], Bl[4][2];
    #pragma unroll
    for (int ct = 0; ct < 4; ++ct) {
        #pragma unroll
        for (int kh = 0; kh < 2; ++kh) {
            size_t boff = (size_t)((ct * 2 + kh) * 64 + lane) * 8;
            Bh[ct][kh] = *(const bf16x8_t*)(w2fh + boff);
            Bl[ct][kh] = *(const bf16x8_t*)(w2fl + boff);
        }
    }
    float bias[4];
    #pragma unroll
    for (int ct = 0; ct < 4; ++ct) bias[ct] = b2[ct * 16 + m];
    int bb_ = blockIdx.x & 63;                  // batch (XCD-pinned)
    int r_  = blockIdx.x >> 6;                  // 0..63 within batch
    int p0 = bb_ * NPTS + r_ * 16 + wave * 4;
    int jv[4];
    #pragma unroll
    for (int pi = 0; pi < 4; ++pi) jv[pi] = idx[(p0 + pi) * 16 + m];
    #pragma unroll
    for (int pi = 0; pi < 4; ++pi) {
        int p = p0 + pi;
        const float* up = u + (size_t)p * 64;
        const float* vp = v + ((size_t)(bb_ << 10) + jv[pi]) * 64;
        bf16x8_t Ah[2], Al[2];
        #pragma unroll
        for (int kh = 0; kh < 2; ++kh) {
            int c0 = kh * 32 + quad * 8;
            float4 ua = *(const float4*)(up + c0);
            float4 ub = *(const float4*)(up + c0 + 4);
            float4 va = *(const float4*)(vp + c0);
            float4 vb = *(const float4*)(vp + c0 + 4);
            float f[8] = {ua.x + va.x, ua.y + va.y, ua.z + va.z, ua.w + va.w,
                          ub.x + vb.x, ub.y + vb.y, ub.z + vb.z, ub.w + vb.w};
            union { ushort_t s[8]; bf16x8_t v8; } H, L;
            #pragma unroll
            for (int e = 0; e < 8; ++e) {
                float g = fmaxf(f[e], 0.f);
                uint_t bits = __float_as_uint(g);
                H.s[e] = (ushort_t)(bits >> 16);
                float hif = __uint_as_float(bits & 0xFFFF0000u);
                L.s[e] = (ushort_t)(__float_as_uint(g - hif) >> 16);
            }
            Ah[kh] = H.v8; Al[kh] = L.v8;
        }
        float val[4];
        #pragma unroll
        for (int ct = 0; ct < 4; ++ct) {
            f32x4_t acc = {0.f, 0.f, 0.f, 0.f};
            acc = __builtin_amdgcn_mfma_f32_16x16x32_bf16(Ah[0], Bh[ct][0], acc, 0, 0, 0);
            acc = __builtin_amdgcn_mfma_f32_16x16x32_bf16(Ah[1], Bh[ct][1], acc, 0, 0, 0);
            acc = __builtin_amdgcn_mfma_f32_16x16x32_bf16(Ah[0], Bl[ct][0], acc, 0, 0, 0);
            acc = __builtin_amdgcn_mfma_f32_16x16x32_bf16(Ah[1], Bl[ct][1], acc, 0, 0, 0);
            acc = __builtin_amdgcn_mfma_f32_16x16x32_bf16(Al[0], Bh[ct][0], acc, 0, 0, 0);
            acc = __builtin_amdgcn_mfma_f32_16x16x32_bf16(Al[1], Bh[ct][1], acc, 0, 0, 0);
            float mm = fmaxf(fmaxf(acc[0], acc[1]), fmaxf(acc[2], acc[3]));
            mm = fmaxf(mm, __shfl_xor(mm, 16, 64));
            mm = fmaxf(mm, __shfl_xor(mm, 32, 64));   // mm now quad-uniform
            val[ct] = mm + bias[ct];
        }
        if constexpr (WSQ) {
            float partial = val[0] * val[0] + val[1] * val[1]
                          + val[2] * val[2] + val[3] * val[3];
            partial += __shfl_xor(partial, 1, 64);
            partial += __shfl_xor(partial, 2, 64);
            partial += __shfl_xor(partial, 4, 64);
            partial += __shfl_xor(partial, 8, 64);
            if (lane == 0) sqout[p] = partial;
        }
        if (quad == 0) {
            #pragma unroll
            for (int ct = 0; ct < 4; ++ct) {
                int o = ct * 16 + m;
                float vv = val[ct];
                if constexpr (WF32) out[(size_t)p * 64 + o] = vv;
                uint_t bits = __float_as_uint(vv);
                oh[(size_t)p * 64 + o] = (ushort_t)(bits >> 16);
                float hif = __uint_as_float(bits & 0xFFFF0000u);
                ol[(size_t)p * 64 + o] = f2bf(vv - hif);
            }
        }
    }
}

// ---------------- final MLP: wave-private, barrier-free (converged structure) ----------------
__global__ __launch_bounds__(128, 2) void mlp_kernel(const ushort_t* __restrict__ xh1,
                                                  const ushort_t* __restrict__ xl1,
                                                  const ushort_t* __restrict__ xh2,
                                                  const ushort_t* __restrict__ xl2,
                                                  const ushort_t* __restrict__ xh3,
                                                  const ushort_t* __restrict__ xl3,
                                                  const ushort_t* __restrict__ w1fh,
                                                  const ushort_t* __restrict__ w1fl,
                                                  const float* __restrict__ mb1,
                                                  const float* __restrict__ mw2, const float* __restrict__ mb2,
                                                  const float* __restrict__ mw3, const float* __restrict__ mb3,
                                                  const float* __restrict__ mw4, const float* __restrict__ mb4,
                                                  float* __restrict__ out) {
    __shared__ float smem[2][128 * 17];      // 8704 B per wave
    int wave = threadIdx.x >> 6, lane = threadIdx.x & 63;
    float* h1w = smem[wave];                 // [128][17]
    float* h2w = smem[wave];                 // [64][17]  overlays h1 (written after all h1 reads)
    float* h3w = smem[wave] + 64 * 17;       // [32][17]  overlays h1's upper half
    int m = lane & 15, quad = lane >> 4;
    int pw = blockIdx.x * 32 + wave * 16;    // this wave's 16 points

    const ushort_t* HS[3] = {xh1, xh2, xh3};
    const ushort_t* LS[3] = {xl1, xl2, xl3};
    bf16x8_t Ah[6], Al[6];
    #pragma unroll
    for (int ks = 0; ks < 6; ++ks) {
        size_t aoff = (size_t)(pw + m) * 64 + (ks & 1) * 32 + quad * 8;
        Ah[ks] = *(const bf16x8_t*)(HS[ks >> 1] + aoff);
        Al[ks] = *(const bf16x8_t*)(LS[ks >> 1] + aoff);
    }
    f32x4_t acc1[8];
    #pragma unroll
    for (int nt = 0; nt < 8; ++nt) acc1[nt] = (f32x4_t){0.f, 0.f, 0.f, 0.f};
    #pragma unroll
    for (int ks = 0; ks < 6; ++ks) {
        bf16x8_t Bh[8], Bl[8];
        #pragma unroll
        for (int nt = 0; nt < 8; ++nt) {
            size_t boff = (size_t)(nt * 6 + ks) * 512 + lane * 8;
            Bh[nt] = *(const bf16x8_t*)(w1fh + boff);
            Bl[nt] = *(const bf16x8_t*)(w1fl + boff);
        }
        #pragma unroll
        for (int nt = 0; nt < 8; ++nt) {
            acc1[nt] = __builtin_amdgcn_mfma_f32_16x16x32_bf16(Ah[ks], Bh[nt], acc1[nt], 0, 0, 0);
            acc1[nt] = __builtin_amdgcn_mfma_f32_16x16x32_bf16(Ah[ks], Bl[nt], acc1[nt], 0, 0, 0);
            acc1[nt] = __builtin_amdgcn_mfma_f32_16x16x32_bf16(Al[ks], Bh[nt], acc1[nt], 0, 0, 0);
        }
    }
    #pragma unroll
    for (int nt = 0; nt < 8; ++nt) {
        float bb = mb1[nt * 16 + m];
        float4 w;
        w.x = fmaxf(acc1[nt][0] + bb, 0.f);
        w.y = fmaxf(acc1[nt][1] + bb, 0.f);
        w.z = fmaxf(acc1[nt][2] + bb, 0.f);
        w.w = fmaxf(acc1[nt][3] + bb, 0.f);
        *(float4*)&h1w[(nt * 16 + m) * 17 + quad * 4] = w;
    }
    float acc2[4][4];
    {
        float4 bb = *(const float4*)&mb2[m * 4];
        #pragma unroll
        for (int i = 0; i < 4; ++i) {
            acc2[i][0] = bb.x; acc2[i][1] = bb.y; acc2[i][2] = bb.z; acc2[i][3] = bb.w;
        }
    }
    for (int cc = 0; cc < 128; cc += 8) {
        float4 wv[8], av4[8];
        #pragma unroll
        for (int q = 0; q < 8; ++q) wv[q] = *(const float4*)&mw2[(cc + q) * 64 + m * 4];
        #pragma unroll
        for (int q = 0; q < 8; ++q) av4[q] = *(const float4*)&h1w[(cc + q) * 17 + quad * 4];
        #pragma unroll
        for (int q = 0; q < 8; ++q) {
            float av[4] = {av4[q].x, av4[q].y, av4[q].z, av4[q].w};
            float bv[4] = {wv[q].x, wv[q].y, wv[q].z, wv[q].w};
            #pragma unroll
            for (int i = 0; i < 4; ++i)
                #pragma unroll
                for (int jj = 0; jj < 4; ++jj)
                    acc2[i][jj] = fmaf(av[i], bv[jj], acc2[i][jj]);
        }
    }
    #pragma unroll
    for (int jj = 0; jj < 4; ++jj) {
        float4 w;
        w.x = fmaxf(acc2[0][jj], 0.f); w.y = fmaxf(acc2[1][jj], 0.f);
        w.z = fmaxf(acc2[2][jj], 0.f); w.w = fmaxf(acc2[3][jj], 0.f);
        *(float4*)&h2w[(m * 4 + jj) * 17 + quad * 4] = w;
    }
    float acc3[4][2];
    {
        float2 bb = *(const float2*)&mb3[m * 2];
        #pragma unroll
        for (int i = 0; i < 4; ++i) { acc3[i][0] = bb.x; acc3[i][1] = bb.y; }
    }
    for (int cc = 0; cc < 64; cc += 8) {
        float2 wv[8]; float4 av4[8];
        #pragma unroll
        for (int q = 0; q < 8; ++q) wv[q] = *(const float2*)&mw3[(cc + q) * 32 + m * 2];
        #pragma unroll
        for (int q = 0; q < 8; ++q) av4[q] = *(const float4*)&h2w[(cc + q) * 17 + quad * 4];
        #pragma unroll
        for (int q = 0; q < 8; ++q) {
            float av[4] = {av4[q].x, av4[q].y, av4[q].z, av4[q].w};
            #pragma unroll
            for (int i = 0; i < 4; ++i) {
                acc3[i][0] = fmaf(av[i], wv[q].x, acc3[i][0]);
                acc3[i][1] = fmaf(av[i], wv[q].y, acc3[i][1]);
            }
        }
    }
    #pragma unroll
    for (int jj = 0; jj < 2; ++jj) {
        float4 w;
        w.x = fmaxf(acc3[0][jj], 0.f); w.y = fmaxf(acc3[1][jj], 0.f);
        w.z = fmaxf(acc3[2][jj], 0.f); w.w = fmaxf(acc3[3][jj], 0.f);
        *(float4*)&h3w[(m * 2 + jj) * 17 + quad * 4] = w;
    }
    if (lane < 16) {
        float z0 = mb4[0], z1 = mb4[1];
        #pragma unroll 8
        for (int c = 0; c < 32; ++c) {
            float h = h3w[c * 17 + lane];
            z0 = fmaf(h, mw4[c * 2 + 0], z0);
            z1 = fmaf(h, mw4[c * 2 + 1], z1);
        }
        float mx = fmaxf(z0, z1);
        float ls = mx + logf(expf(z0 - mx) + expf(z1 - mx));
        float2 o; o.x = z0 - ls; o.y = z1 - ls;
        *(float2*)&out[(size_t)(pw + lane) * 2] = o;
    }
}

extern "C" void kernel_launch(void* const* d_in, const int* in_sizes, int n_in,
                              void* d_out, int out_size, void* d_ws, size_t ws_size,
                              hipStream_t stream) {
    const float* x0   = (const float*)d_in[0];
    const float* c1w1 = (const float*)d_in[1];  const float* c1b1 = (const float*)d_in[2];
    const float* c1w2 = (const float*)d_in[3];  const float* c1b2 = (const float*)d_in[4];
    const float* c2w1 = (const float*)d_in[5];  const float* c2b1 = (const float*)d_in[6];
    const float* c2w2 = (const float*)d_in[7];  const float* c2b2 = (const float*)d_in[8];
    const float* c3w1 = (const float*)d_in[9];  const float* c3b1 = (const float*)d_in[10];
    const float* c3w2 = (const float*)d_in[11]; const float* c3b2 = (const float*)d_in[12];
    const float* mw1  = (const float*)d_in[13]; const float* mb1  = (const float*)d_in[14];
    const float* mw2  = (const float*)d_in[15]; const float* mb2  = (const float*)d_in[16];
    const float* mw3  = (const float*)d_in[17]; const float* mb3  = (const float*)d_in[18];
    const float* mw4  = (const float*)d_in[19]; const float* mb4  = (const float*)d_in[20];

    float* ws = (float*)d_ws;
    const size_t NF = (size_t)NPOINTS * 64;
    float* x1 = ws;                      // fp32 (uv L2 input)
    float* x2 = x1 + NF;                 // fp32 (uv L3 input)
    ushort_t* xh3 = (ushort_t*)(x2 + NF);
    ushort_t* xl3 = xh3 + NF;
    float* u  = (float*)(xl3 + NF);
    float* v  = u + NF;
    float* sq = v + NF;
    int*  idx = (int*)(sq + NPOINTS);
    ushort_t* xh1 = (ushort_t*)(idx + (size_t)NPOINTS * KNB);
    ushort_t* xl1 = xh1 + NF;
    ushort_t* xh2 = xl1 + NF;
    ushort_t* xl2 = xh2 + NF;
    ushort_t* w1fh = xl2 + NF;
    ushort_t* w1fl = w1fh + 128 * 192;
    ushort_t* w2fh = w1fl + 128 * 192;   // 3 layers x 4096
    ushort_t* w2fl = w2fh + 3 * 4096;
    float* out = (float*)d_out;

    // ---- fused weight prep ----
    prep_kernel<<<144, 256, 0, stream>>>(mw1, c1w2, c2w2, c3w2,
                                         w1fh, w1fl, w2fh, w2fl);
    // ---- layer 1 (C_in = 1): sort-window knn ----
    knn1_sort_kernel<<<NB, 256, 0, stream>>>(x0, idx);
    uv1_kernel<<<1024, 256, 0, stream>>>(x0, c1w1, c1b1, u, v);
    edge_mfma_kernel<true, true><<<NPOINTS / 16, 256, 0, stream>>>(
        u, v, idx, w2fh, w2fl, c1b2, x1, xh1, xl1, sq);
    // ---- layer 2: fused MFMA knn on xh1/xl1 (writes idx directly) ----
    knn_mfma_kernel<<<NB * 16, 256, 0, stream>>>(xh1, xl1, sq, idx);
    uv_gemm_kernel<<<NPOINTS / 64, 256, 0, stream>>>(x1, c2w1, c2b1, u, v);
    edge_mfma_kernel<true, true><<<NPOINTS / 16, 256, 0, stream>>>(
        u, v, idx, w2fh + 4096, w2fl + 4096, c2b2, x2, xh2, xl2, sq);
    // ---- layer 3: fused MFMA knn on xh2/xl2 ----
    knn_mfma_kernel<<<NB * 16, 256, 0, stream>>>(xh2, xl2, sq, idx);
    uv_gemm_kernel<<<NPOINTS / 64, 256, 0, stream>>>(x2, c3w1, c3b1, u, v);
    edge_mfma_kernel<false, false><<<NPOINTS / 16, 256, 0, stream>>>(
        u, v, idx, w2fh + 8192, w2fl + 8192, c3b2, nullptr, xh3, xl3, nullptr);
    // ---- final MLP + log_softmax ----
    mlp_kernel<<<NPOINTS / 32, 128, 0, stream>>>(xh1, xl1, xh2, xl2, xh3, xl3,
                                                 w1fh, w1fl, mb1, mw2, mb2,
                                                 mw3, mb3, mw4, mb4, out);
}

// Round 18
// 554.374 us; speedup vs baseline: 1.0711x; 1.0364x over previous
//
#include <hip/hip_runtime.h>
#include <math.h>

typedef unsigned short ushort_t;
typedef unsigned int uint_t;
typedef unsigned long long u64_t;
typedef __bf16 bf16x8_t __attribute__((ext_vector_type(8)));
typedef float f32x4_t __attribute__((ext_vector_type(4)));

static constexpr int NPTS = 1024;
static constexpr int NB = 64;
static constexpr int NPOINTS = NB * NPTS;   // 65536
static constexpr int KNB = 16;

__device__ __forceinline__ ushort_t f2bf(float f) {
    uint_t u = __float_as_uint(f);
    uint_t r = (u + 0x7FFFu + ((u >> 16) & 1u)) >> 16;
    return (ushort_t)r;
}
// pack distance (clamped >=0, 22 bits kept) + batch-local j (10 bits).
__device__ __forceinline__ uint_t packdj(float d, int j) {
    return (__float_as_uint(fmaxf(d, 0.f)) & 0xFFFFFC00u) | (uint_t)j;
}
// single-instruction median: for sorted L[k-1]<=L[k], post-insert
// L'[k] = med3(L[k-1], L[k], c). One VOP3 per step; all steps independent.
__device__ __forceinline__ uint_t med3u(uint_t a, uint_t b, uint_t c) {
    uint_t d;
    asm("v_med3_u32 %0, %1, %2, %3" : "=v"(d) : "v"(a), "v"(b), "v"(c));
    return d;
}
__device__ __forceinline__ void insert16(uint_t* L, uint_t c) {
    #pragma unroll
    for (int k = 15; k > 0; --k)
        L[k] = med3u(L[k - 1], L[k], c);
    L[0] = L[0] < c ? L[0] : c;
}
// monotone float->uint order transform
__device__ __forceinline__ uint_t f2ord(float f) {
    uint_t u = __float_as_uint(f);
    return (u & 0x80000000u) ? ~u : (u ^ 0x80000000u);
}

// ---------------- fused weight prep: w1mlp + 3x w2 (frag-contig) + layer1 uv consts ----
__global__ __launch_bounds__(256) void prep_kernel(const float* __restrict__ mw1,
                                                   const float* __restrict__ c1w2,
                                                   const float* __restrict__ c2w2,
                                                   const float* __restrict__ c3w2,
                                                   const float* __restrict__ c1w1,
                                                   const float* __restrict__ c1b1,
                                                   ushort_t* __restrict__ w1fh,
                                                   ushort_t* __restrict__ w1fl,
                                                   ushort_t* __restrict__ w2fh,  // 3 layers concat
                                                   ushort_t* __restrict__ w2fl,
                                                   float* __restrict__ wuv) {    // [3][64][16]
    int blk = blockIdx.x;
    if (blk < 96) {
        int t = blk * 256 + threadIdx.x;         // 0..24575
        int e = t & 7;
        int lane = (t >> 3) & 63;
        int fs = t >> 9;                         // frag id = nt*6+ks, 0..47
        int nt = fs / 6, ks = fs - nt * 6;
        int m = lane & 15, quad = lane >> 4;
        int k = ks * 32 + quad * 8 + e;
        int n = nt * 16 + m;
        float w = mw1[k * 128 + n];
        uint_t bits = __float_as_uint(w);
        float hif = __uint_as_float(bits & 0xFFFF0000u);
        w1fh[t] = (ushort_t)(bits >> 16);
        w1fl[t] = f2bf(w - hif);
    } else if (blk < 144) {
        int layer = (blk - 96) >> 4;             // 0..2
        const float* w2 = layer == 0 ? c1w2 : (layer == 1 ? c2w2 : c3w2);
        int t = ((blk - 96) & 15) * 256 + threadIdx.x;   // 0..4095
        int e = t & 7;
        int lane = (t >> 3) & 63;
        int fs = t >> 9;                         // frag id = ct*2+kh, 0..7
        int ct = fs >> 1, kh = fs & 1;
        int m = lane & 15, quad = lane >> 4;
        int k = kh * 32 + quad * 8 + e;
        int n = ct * 16 + m;
        float w = w2[k * 64 + n];
        uint_t bits = __float_as_uint(w);
        float hif = __uint_as_float(bits & 0xFFFF0000u);
        w2fh[layer * 4096 + t] = (ushort_t)(bits >> 16);
        w2fl[layer * 4096 + t] = f2bf(w - hif);
    } else {
        // layer-1 uv constants: wuv[arr*1024 + lane*16 + kh*8 + e],
        // arr 0: w1a-w1b, 1: w1b, 2: b1; channel c = kh*32 + (lane>>4)*8 + e
        for (int s = threadIdx.x; s < 3072; s += 256) {
            int arr = s >> 10, r = s & 1023;
            int lane = r >> 4, ce = r & 15;
            int kh = ce >> 3, e = ce & 7;
            int quad = lane >> 4;
            int c = kh * 32 + quad * 8 + e;
            float val = (arr == 0) ? (c1w1[c] - c1w1[64 + c])
                      : (arr == 1) ? c1w1[64 + c] : c1b1[c];
            wuv[s] = val;
        }
    }
}

// ---------------- layer-1 knn (C=1): bitonic sort + +/-16 window ----------------
__global__ __launch_bounds__(256) void knn1_sort_kernel(const float* __restrict__ pts,
                                                        int* __restrict__ idx_out) {
    __shared__ u64_t keys[NPTS];
    int b = blockIdx.x;
    int t = threadIdx.x;
    const float* base = pts + (size_t)b * NPTS;
    for (int s = t; s < NPTS; s += 256)
        keys[s] = ((u64_t)f2ord(base[s]) << 32) | (uint_t)s;
    for (int k = 2; k <= NPTS; k <<= 1) {
        for (int j2 = k >> 1; j2 > 0; j2 >>= 1) {
            __syncthreads();
            for (int i = t; i < NPTS; i += 256) {
                int ix = i ^ j2;
                if (ix > i) {
                    bool asc = ((i & k) == 0);
                    u64_t a = keys[i], c = keys[ix];
                    if ((a > c) == asc) { keys[i] = c; keys[ix] = a; }
                }
            }
        }
    }
    __syncthreads();
    for (int s = t; s < NPTS; s += 256) {
        u64_t me = keys[s];
        int jme = (int)(me & 0x3FFu);
        uint_t mo = (uint_t)(me >> 32);
        uint_t mu = (mo & 0x80000000u) ? (mo ^ 0x80000000u) : ~mo;
        float xs = __uint_as_float(mu);
        uint_t lst[KNB];
        #pragma unroll
        for (int k = 0; k < KNB; ++k) lst[k] = 0xFFFFFFFFu;
        int lo = s - 16; if (lo < 0) lo = 0;
        int hi = s + 16; if (hi > NPTS - 1) hi = NPTS - 1;
        for (int q = lo; q <= hi; ++q) {
            u64_t o = keys[q];
            uint_t oo = (uint_t)(o >> 32);
            uint_t ou = (oo & 0x80000000u) ? (oo ^ 0x80000000u) : ~oo;
            float xo = __uint_as_float(ou);
            float d = (xs - xo) * (xs - xo);
            insert16(lst, packdj(d, (int)(o & 0x3FFu)));
        }
        int* op = idx_out + ((size_t)b * NPTS + jme) * KNB;
        #pragma unroll
        for (int k = 0; k < KNB; ++k) op[k] = (int)(lst[k] & 0x3FFu);
    }
}

// ---------------- MFMA knn (C=64), FUSED: block = (batch, i-block), wave = chunk ----
__global__ __launch_bounds__(256, 4) void knn_mfma_kernel(const ushort_t* __restrict__ xh,
                                                          const ushort_t* __restrict__ xl,
                                                          const float* __restrict__ sq,
                                                          int* __restrict__ idx_out) {
    constexpr int JC = NPTS / 4;                 // 256 j per chunk(=wave)
    __shared__ uint_t dbuf[4][16 * 68];
    __shared__ float sqs[4][JC];
    __shared__ uint_t mlst[4][64][17];           // [chunk][i-lane][k], stride-17
    int b    = blockIdx.x & 63;
    int ib   = blockIdx.x >> 6;                  // 0..15
    int wave = threadIdx.x >> 6;                 // = chunk
    int lane = threadIdx.x & 63;
    int i0   = b * NPTS + ib * 64;
    int m = lane & 15, quad = lane >> 4;
    int j0c = wave * JC;

    for (int t = lane; t < JC; t += 64) sqs[wave][t] = sq[b * NPTS + j0c + t];

    bf16x8_t Ah[4][2], Al[4][2];
    #pragma unroll
    for (int it = 0; it < 4; ++it) {
        #pragma unroll
        for (int kh = 0; kh < 2; ++kh) {
            size_t off = ((size_t)(i0 + it * 16 + m)) * 64 + kh * 32 + quad * 8;
            Ah[it][kh] = *(const bf16x8_t*)(xh + off);
            Al[it][kh] = *(const bf16x8_t*)(xl + off);
        }
    }
    float4 sqi[4];
    #pragma unroll
    for (int it = 0; it < 4; ++it)
        sqi[it] = *(const float4*)&sq[i0 + it * 16 + quad * 4];

    uint_t lst[KNB];
    #pragma unroll
    for (int k = 0; k < KNB; ++k) lst[k] = 0xFFFFFFFFu;

    for (int g = 0; g < JC / 16; ++g) {
        int jg = j0c + g * 16;                       // batch-local j base
        size_t boff = ((size_t)(b * NPTS + jg + m)) * 64 + quad * 8;
        bf16x8_t Bh0 = *(const bf16x8_t*)(xh + boff);
        bf16x8_t Bh1 = *(const bf16x8_t*)(xh + boff + 32);
        bf16x8_t Bl0 = *(const bf16x8_t*)(xl + boff);
        bf16x8_t Bl1 = *(const bf16x8_t*)(xl + boff + 32);
        float sqj = sqs[wave][g * 16 + m];
        int jm = jg + m;
        #pragma unroll
        for (int it = 0; it < 4; ++it) {
            f32x4_t acc = {0.f, 0.f, 0.f, 0.f};
            acc = __builtin_amdgcn_mfma_f32_16x16x32_bf16(Ah[it][0], Bh0, acc, 0, 0, 0);
            acc = __builtin_amdgcn_mfma_f32_16x16x32_bf16(Ah[it][1], Bh1, acc, 0, 0, 0);
            acc = __builtin_amdgcn_mfma_f32_16x16x32_bf16(Ah[it][0], Bl0, acc, 0, 0, 0);
            acc = __builtin_amdgcn_mfma_f32_16x16x32_bf16(Ah[it][1], Bl1, acc, 0, 0, 0);
            acc = __builtin_amdgcn_mfma_f32_16x16x32_bf16(Al[it][0], Bh0, acc, 0, 0, 0);
            acc = __builtin_amdgcn_mfma_f32_16x16x32_bf16(Al[it][1], Bh1, acc, 0, 0, 0);
            uint4 pv;
            pv.x = packdj(sqi[it].x + sqj - 2.0f * acc[0], jm);
            pv.y = packdj(sqi[it].y + sqj - 2.0f * acc[1], jm);
            pv.z = packdj(sqi[it].z + sqj - 2.0f * acc[2], jm);
            pv.w = packdj(sqi[it].w + sqj - 2.0f * acc[3], jm);
            *(uint4*)&dbuf[wave][m * 68 + it * 16 + quad * 4] = pv;
        }
        // dbuf is wave-private: ds-ordering within the wave, no barrier.
        #pragma unroll
        for (int jj = 0; jj < 16; ++jj)
            insert16(lst, dbuf[wave][jj * 68 + lane]);
    }
    #pragma unroll
    for (int k = 0; k < KNB; ++k) mlst[wave][lane][k] = lst[k];
    __syncthreads();
    if (wave == 0) {
        uint_t fin[KNB];
        #pragma unroll
        for (int k = 0; k < KNB; ++k) fin[k] = 0xFFFFFFFFu;
        #pragma unroll
        for (int c = 0; c < 4; ++c)
            #pragma unroll
            for (int k = 0; k < KNB; ++k)
                insert16(fin, mlst[c][lane][k]);
        int* op = idx_out + (size_t)(i0 + lane) * KNB;
        #pragma unroll
        for (int k = 0; k < KNB; ++k) op[k] = (int)(fin[k] & 0x3FFu);
    }
}

// ---------------- uv GEMM (CIN=64) ----------------
__global__ __launch_bounds__(256) void uv_gemm_kernel(const float* __restrict__ x,
                                                      const float* __restrict__ w1,
                                                      const float* __restrict__ b1,
                                                      float* __restrict__ u,
                                                      float* __restrict__ v) {
    __shared__ float As[64 * 68];
    __shared__ float Bs[64 * 128];
    int t = threadIdx.x;
    int p0 = blockIdx.x * 64;
    for (int g = t; g < 64 * 16; g += 256) {
        int c = g >> 4, o4 = (g & 15) * 4;
        float4 wa = *(const float4*)&w1[c * 64 + o4];
        float4 wb = *(const float4*)&w1[(64 + c) * 64 + o4];
        float4 d; d.x = wa.x - wb.x; d.y = wa.y - wb.y; d.z = wa.z - wb.z; d.w = wa.w - wb.w;
        *(float4*)&Bs[c * 128 + o4] = d;
    }
    for (int g = t; g < 64 * 16; g += 256) {
        int c = g >> 4, o4 = (g & 15) * 4;
        *(float4*)&Bs[c * 128 + 64 + o4] = *(const float4*)&w1[(64 + c) * 64 + o4];
    }
    {
        int pq = t >> 4, cq = t & 15;
        const float* xp = x + (size_t)(p0 + pq * 4) * 64 + cq * 4;
        float4 r0 = *(const float4*)&xp[0 * 64];
        float4 r1 = *(const float4*)&xp[1 * 64];
        float4 r2 = *(const float4*)&xp[2 * 64];
        float4 r3 = *(const float4*)&xp[3 * 64];
        float4 c0; c0.x = r0.x; c0.y = r1.x; c0.z = r2.x; c0.w = r3.x;
        float4 c1; c1.x = r0.y; c1.y = r1.y; c1.z = r2.y; c1.w = r3.y;
        float4 c2; c2.x = r0.z; c2.y = r1.z; c2.z = r2.z; c2.w = r3.z;
        float4 c3; c3.x = r0.w; c3.y = r1.w; c3.z = r2.w; c3.w = r3.w;
        *(float4*)&As[(cq * 4 + 0) * 68 + pq * 4] = c0;
        *(float4*)&As[(cq * 4 + 1) * 68 + pq * 4] = c1;
        *(float4*)&As[(cq * 4 + 2) * 68 + pq * 4] = c2;
        *(float4*)&As[(cq * 4 + 3) * 68 + pq * 4] = c3;
    }
    __syncthreads();
    int rg = t >> 4;
    int cg = t & 15;
    float acc[4][8];
    #pragma unroll
    for (int i = 0; i < 4; ++i)
        #pragma unroll
        for (int jj = 0; jj < 8; ++jj) acc[i][jj] = 0.f;
    #pragma unroll 4
    for (int c = 0; c < 64; ++c) {
        float4 a4 = *(const float4*)&As[c * 68 + rg * 4];
        float4 b0 = *(const float4*)&Bs[c * 128 + cg * 8];
        float4 b4 = *(const float4*)&Bs[c * 128 + cg * 8 + 4];
        float av[4] = {a4.x, a4.y, a4.z, a4.w};
        float bv[8] = {b0.x, b0.y, b0.z, b0.w, b4.x, b4.y, b4.z, b4.w};
        #pragma unroll
        for (int i = 0; i < 4; ++i)
            #pragma unroll
            for (int jj = 0; jj < 8; ++jj)
                acc[i][jj] = fmaf(av[i], bv[jj], acc[i][jj]);
    }
    if (cg < 8) {
        float4 bb0 = *(const float4*)&b1[cg * 8];
        float4 bb1 = *(const float4*)&b1[cg * 8 + 4];
        #pragma unroll
        for (int i = 0; i < 4; ++i) {
            size_t p = p0 + rg * 4 + i;
            float4 o0; o0.x = acc[i][0] + bb0.x; o0.y = acc[i][1] + bb0.y;
                       o0.z = acc[i][2] + bb0.z; o0.w = acc[i][3] + bb0.w;
            float4 o1; o1.x = acc[i][4] + bb1.x; o1.y = acc[i][5] + bb1.y;
                       o1.z = acc[i][6] + bb1.z; o1.w = acc[i][7] + bb1.w;
            *(float4*)&u[p * 64 + cg * 8]     = o0;
            *(float4*)&u[p * 64 + cg * 8 + 4] = o1;
        }
    } else {
        int o = (cg - 8) * 8;
        #pragma unroll
        for (int i = 0; i < 4; ++i) {
            size_t p = p0 + rg * 4 + i;
            float4 o0; o0.x = acc[i][0]; o0.y = acc[i][1]; o0.z = acc[i][2]; o0.w = acc[i][3];
            float4 o1; o1.x = acc[i][4]; o1.y = acc[i][5]; o1.z = acc[i][6]; o1.w = acc[i][7];
            *(float4*)&v[p * 64 + o]     = o0;
            *(float4*)&v[p * 64 + o + 4] = o1;
        }
    }
}

// ---------------- edge1 MFMA (layer 1, C_in=1): u/v never materialized ----------------
// relu(u_i+v_j)[c] = relu(x_i*wd[c] + x_j*wb[c] + b1[c]) -- rank-1 in scalars.
// Reads: x_i (wave-uniform), x_j (4 B gather), per-lane consts from wuv.
__global__ __launch_bounds__(256) void edge1_mfma_kernel(const float* __restrict__ x0,
                                                         const int* __restrict__ idx,
                                                         const ushort_t* __restrict__ w2fh,
                                                         const ushort_t* __restrict__ w2fl,
                                                         const float* __restrict__ wuv,
                                                         const float* __restrict__ b2,
                                                         float* __restrict__ out,
                                                         ushort_t* __restrict__ oh,
                                                         ushort_t* __restrict__ ol,
                                                         float* __restrict__ sqout) {
    int wave = threadIdx.x >> 6, lane = threadIdx.x & 63;
    int m = lane & 15, quad = lane >> 4;
    bf16x8_t Bh[4][2], Bl[4][2];
    #pragma unroll
    for (int ct = 0; ct < 4; ++ct) {
        #pragma unroll
        for (int kh = 0; kh < 2; ++kh) {
            size_t boff = (size_t)((ct * 2 + kh) * 64 + lane) * 8;
            Bh[ct][kh] = *(const bf16x8_t*)(w2fh + boff);
            Bl[ct][kh] = *(const bf16x8_t*)(w2fl + boff);
        }
    }
    float wdv[16], wbv[16], bbv[16];
    #pragma unroll
    for (int q = 0; q < 4; ++q) {
        *(float4*)&wdv[q * 4] = *(const float4*)&wuv[lane * 16 + q * 4];
        *(float4*)&wbv[q * 4] = *(const float4*)&wuv[1024 + lane * 16 + q * 4];
        *(float4*)&bbv[q * 4] = *(const float4*)&wuv[2048 + lane * 16 + q * 4];
    }
    float bias[4];
    #pragma unroll
    for (int ct = 0; ct < 4; ++ct) bias[ct] = b2[ct * 16 + m];
    int bb_ = blockIdx.x & 63;                  // batch (XCD-pinned)
    int r_  = blockIdx.x >> 6;                  // 0..63 within batch
    int p0 = bb_ * NPTS + r_ * 16 + wave * 4;
    int jv[4];
    #pragma unroll
    for (int pi = 0; pi < 4; ++pi) jv[pi] = idx[(p0 + pi) * 16 + m];
    float xj4[4];
    #pragma unroll
    for (int pi = 0; pi < 4; ++pi) xj4[pi] = x0[(bb_ << 10) + jv[pi]];
    #pragma unroll
    for (int pi = 0; pi < 4; ++pi) {
        int p = p0 + pi;
        float xi = x0[p];                       // wave-uniform
        float xj = xj4[pi];                     // per A-row (neighbor m)
        bf16x8_t Ah[2], Al[2];
        #pragma unroll
        for (int kh = 0; kh < 2; ++kh) {
            union { ushort_t s[8]; bf16x8_t v8; } H, L;
            #pragma unroll
            for (int e = 0; e < 8; ++e) {
                int ce = kh * 8 + e;
                float g = fmaxf(fmaf(xi, wdv[ce], fmaf(xj, wbv[ce], bbv[ce])), 0.f);
                uint_t bits = __float_as_uint(g);
                H.s[e] = (ushort_t)(bits >> 16);
                float hif = __uint_as_float(bits & 0xFFFF0000u);
                L.s[e] = (ushort_t)(__float_as_uint(g - hif) >> 16);
            }
            Ah[kh] = H.v8; Al[kh] = L.v8;
        }
        float val[4];
        #pragma unroll
        for (int ct = 0; ct < 4; ++ct) {
            f32x4_t acc = {0.f, 0.f, 0.f, 0.f};
            acc = __builtin_amdgcn_mfma_f32_16x16x32_bf16(Ah[0], Bh[ct][0], acc, 0, 0, 0);
            acc = __builtin_amdgcn_mfma_f32_16x16x32_bf16(Ah[1], Bh[ct][1], acc, 0, 0, 0);
            acc = __builtin_amdgcn_mfma_f32_16x16x32_bf16(Ah[0], Bl[ct][0], acc, 0, 0, 0);
            acc = __builtin_amdgcn_mfma_f32_16x16x32_bf16(Ah[1], Bl[ct][1], acc, 0, 0, 0);
            acc = __builtin_amdgcn_mfma_f32_16x16x32_bf16(Al[0], Bh[ct][0], acc, 0, 0, 0);
            acc = __builtin_amdgcn_mfma_f32_16x16x32_bf16(Al[1], Bh[ct][1], acc, 0, 0, 0);
            float mm = fmaxf(fmaxf(acc[0], acc[1]), fmaxf(acc[2], acc[3]));
            mm = fmaxf(mm, __shfl_xor(mm, 16, 64));
            mm = fmaxf(mm, __shfl_xor(mm, 32, 64));
            val[ct] = mm + bias[ct];
        }
        {   // fused sqnorm (layer-1 edge always feeds knn2)
            float partial = val[0] * val[0] + val[1] * val[1]
                          + val[2] * val[2] + val[3] * val[3];
            partial += __shfl_xor(partial, 1, 64);
            partial += __shfl_xor(partial, 2, 64);
            partial += __shfl_xor(partial, 4, 64);
            partial += __shfl_xor(partial, 8, 64);
            if (lane == 0) sqout[p] = partial;
        }
        if (quad == 0) {
            #pragma unroll
            for (int ct = 0; ct < 4; ++ct) {
                int o = ct * 16 + m;
                float vv = val[ct];
                out[(size_t)p * 64 + o] = vv;
                uint_t bits = __float_as_uint(vv);
                oh[(size_t)p * 64 + o] = (ushort_t)(bits >> 16);
                float hif = __uint_as_float(bits & 0xFFFF0000u);
                ol[(size_t)p * 64 + o] = f2bf(vv - hif);
            }
        }
    }
}

// ---------------- edge MFMA (layers 2/3): wave = 1 point/step, prefab w2 frags ----
template<bool WF32, bool WSQ>
__global__ __launch_bounds__(256) void edge_mfma_kernel(const float* __restrict__ u,
                                                        const float* __restrict__ v,
                                                        const int* __restrict__ idx,
                                                        const ushort_t* __restrict__ w2fh,
                                                        const ushort_t* __restrict__ w2fl,
                                                        const float* __restrict__ b2,
                                                        float* __restrict__ out,
                                                        ushort_t* __restrict__ oh,
                                                        ushort_t* __restrict__ ol,
                                                        float* __restrict__ sqout) {
    int wave = threadIdx.x >> 6, lane = threadIdx.x & 63;
    int m = lane & 15, quad = lane >> 4;
    bf16x8_t Bh[4][2], Bl[4][2];
    #pragma unroll
    for (int ct = 0; ct < 4; ++ct) {
        #pragma unroll
        for (int kh = 0; kh < 2; ++kh) {
            size_t boff = (size_t)((ct * 2 + kh) * 64 + lane) * 8;
            Bh[ct][kh] = *(const bf16x8_t*)(w2fh + boff);
            Bl[ct][kh] = *(const bf16x8_t*)(w2fl + boff);
        }
    }
    float bias[4];
    #pragma unroll
    for (int ct = 0; ct < 4; ++ct) bias[ct] = b2[ct * 16 + m];
    int bb_ = blockIdx.x & 63;                  // batch (XCD-pinned)
    int r_  = blockIdx.x >> 6;                  // 0..63 within batch
    int p0 = bb_ * NPTS + r_ * 16 + wave * 4;
    int jv[4];
    #pragma unroll
    for (int pi = 0; pi < 4; ++pi) jv[pi] = idx[(p0 + pi) * 16 + m];
    #pragma unroll
    for (int pi = 0; pi < 4; ++pi) {
        int p = p0 + pi;
        const float* up = u + (size_t)p * 64;
        const float* vp = v + ((size_t)(bb_ << 10) + jv[pi]) * 64;
        bf16x8_t Ah[2], Al[2];
        #pragma unroll
        for (int kh = 0; kh < 2; ++kh) {
            int c0 = kh * 32 + quad * 8;
            float4 ua = *(const float4*)(up + c0);
            float4 ub = *(const float4*)(up + c0 + 4);
            float4 va = *(const float4*)(vp + c0);
            float4 vb = *(const float4*)(vp + c0 + 4);
            float f[8] = {ua.x + va.x, ua.y + va.y, ua.z + va.z, ua.w + va.w,
                          ub.x + vb.x, ub.y + vb.y, ub.z + vb.z, ub.w + vb.w};
            union { ushort_t s[8]; bf16x8_t v8; } H, L;
            #pragma unroll
            for (int e = 0; e < 8; ++e) {
                float g = fmaxf(f[e], 0.f);
                uint_t bits = __float_as_uint(g);
                H.s[e] = (ushort_t)(bits >> 16);
                float hif = __uint_as_float(bits & 0xFFFF0000u);
                L.s[e] = (ushort_t)(__float_as_uint(g - hif) >> 16);
            }
            Ah[kh] = H.v8; Al[kh] = L.v8;
        }
        float val[4];
        #pragma unroll
        for (int ct = 0; ct < 4; ++ct) {
            f32x4_t acc = {0.f, 0.f, 0.f, 0.f};
            acc = __builtin_amdgcn_mfma_f32_16x16x32_bf16(Ah[0], Bh[ct][0], acc, 0, 0, 0);
            acc = __builtin_amdgcn_mfma_f32_16x16x32_bf16(Ah[1], Bh[ct][1], acc, 0, 0, 0);
            acc = __builtin_amdgcn_mfma_f32_16x16x32_bf16(Ah[0], Bl[ct][0], acc, 0, 0, 0);
            acc = __builtin_amdgcn_mfma_f32_16x16x32_bf16(Ah[1], Bl[ct][1], acc, 0, 0, 0);
            acc = __builtin_amdgcn_mfma_f32_16x16x32_bf16(Al[0], Bh[ct][0], acc, 0, 0, 0);
            acc = __builtin_amdgcn_mfma_f32_16x16x32_bf16(Al[1], Bh[ct][1], acc, 0, 0, 0);
            float mm = fmaxf(fmaxf(acc[0], acc[1]), fmaxf(acc[2], acc[3]));
            mm = fmaxf(mm, __shfl_xor(mm, 16, 64));
            mm = fmaxf(mm, __shfl_xor(mm, 32, 64));   // mm now quad-uniform
            val[ct] = mm + bias[ct];
        }
        if constexpr (WSQ) {
            float partial = val[0] * val[0] + val[1] * val[1]
                          + val[2] * val[2] + val[3] * val[3];
            partial += __shfl_xor(partial, 1, 64);
            partial += __shfl_xor(partial, 2, 64);
            partial += __shfl_xor(partial, 4, 64);
            partial += __shfl_xor(partial, 8, 64);
            if (lane == 0) sqout[p] = partial;
        }
        if (quad == 0) {
            #pragma unroll
            for (int ct = 0; ct < 4; ++ct) {
                int o = ct * 16 + m;
                float vv = val[ct];
                if constexpr (WF32) out[(size_t)p * 64 + o] = vv;
                uint_t bits = __float_as_uint(vv);
                oh[(size_t)p * 64 + o] = (ushort_t)(bits >> 16);
                float hif = __uint_as_float(bits & 0xFFFF0000u);
                ol[(size_t)p * 64 + o] = f2bf(vv - hif);
            }
        }
    }
}

// ---------------- final MLP: wave-private, barrier-free (converged structure) ----------------
__global__ __launch_bounds__(128, 2) void mlp_kernel(const ushort_t* __restrict__ xh1,
                                                  const ushort_t* __restrict__ xl1,
                                                  const ushort_t* __restrict__ xh2,
                                                  const ushort_t* __restrict__ xl2,
                                                  const ushort_t* __restrict__ xh3,
                                                  const ushort_t* __restrict__ xl3,
                                                  const ushort_t* __restrict__ w1fh,
                                                  const ushort_t* __restrict__ w1fl,
                                                  const float* __restrict__ mb1,
                                                  const float* __restrict__ mw2, const float* __restrict__ mb2,
                                                  const float* __restrict__ mw3, const float* __restrict__ mb3,
                                                  const float* __restrict__ mw4, const float* __restrict__ mb4,
                                                  float* __restrict__ out) {
    __shared__ float smem[2][128 * 17];      // 8704 B per wave
    int wave = threadIdx.x >> 6, lane = threadIdx.x & 63;
    float* h1w = smem[wave];                 // [128][17]
    float* h2w = smem[wave];                 // [64][17]  overlays h1 (written after all h1 reads)
    float* h3w = smem[wave] + 64 * 17;       // [32][17]  overlays h1's upper half
    int m = lane & 15, quad = lane >> 4;
    int pw = blockIdx.x * 32 + wave * 16;    // this wave's 16 points

    const ushort_t* HS[3] = {xh1, xh2, xh3};
    const ushort_t* LS[3] = {xl1, xl2, xl3};
    bf16x8_t Ah[6], Al[6];
    #pragma unroll
    for (int ks = 0; ks < 6; ++ks) {
        size_t aoff = (size_t)(pw + m) * 64 + (ks & 1) * 32 + quad * 8;
        Ah[ks] = *(const bf16x8_t*)(HS[ks >> 1] + aoff);
        Al[ks] = *(const bf16x8_t*)(LS[ks >> 1] + aoff);
    }
    f32x4_t acc1[8];
    #pragma unroll
    for (int nt = 0; nt < 8; ++nt) acc1[nt] = (f32x4_t){0.f, 0.f, 0.f, 0.f};
    #pragma unroll
    for (int ks = 0; ks < 6; ++ks) {
        bf16x8_t Bh[8], Bl[8];
        #pragma unroll
        for (int nt = 0; nt < 8; ++nt) {
            size_t boff = (size_t)(nt * 6 + ks) * 512 + lane * 8;
            Bh[nt] = *(const bf16x8_t*)(w1fh + boff);
            Bl[nt] = *(const bf16x8_t*)(w1fl + boff);
        }
        #pragma unroll
        for (int nt = 0; nt < 8; ++nt) {
            acc1[nt] = __builtin_amdgcn_mfma_f32_16x16x32_bf16(Ah[ks], Bh[nt], acc1[nt], 0, 0, 0);
            acc1[nt] = __builtin_amdgcn_mfma_f32_16x16x32_bf16(Ah[ks], Bl[nt], acc1[nt], 0, 0, 0);
            acc1[nt] = __builtin_amdgcn_mfma_f32_16x16x32_bf16(Al[ks], Bh[nt], acc1[nt], 0, 0, 0);
        }
    }
    #pragma unroll
    for (int nt = 0; nt < 8; ++nt) {
        float bb = mb1[nt * 16 + m];
        float4 w;
        w.x = fmaxf(acc1[nt][0] + bb, 0.f);
        w.y = fmaxf(acc1[nt][1] + bb, 0.f);
        w.z = fmaxf(acc1[nt][2] + bb, 0.f);
        w.w = fmaxf(acc1[nt][3] + bb, 0.f);
        *(float4*)&h1w[(nt * 16 + m) * 17 + quad * 4] = w;
    }
    float acc2[4][4];
    {
        float4 bb = *(const float4*)&mb2[m * 4];
        #pragma unroll
        for (int i = 0; i < 4; ++i) {
            acc2[i][0] = bb.x; acc2[i][1] = bb.y; acc2[i][2] = bb.z; acc2[i][3] = bb.w;
        }
    }
    for (int cc = 0; cc < 128; cc += 8) {
        float4 wv[8], av4[8];
        #pragma unroll
        for (int q = 0; q < 8; ++q) wv[q] = *(const float4*)&mw2[(cc + q) * 64 + m * 4];
        #pragma unroll
        for (int q = 0; q < 8; ++q) av4[q] = *(const float4*)&h1w[(cc + q) * 17 + quad * 4];
        #pragma unroll
        for (int q = 0; q < 8; ++q) {
            float av[4] = {av4[q].x, av4[q].y, av4[q].z, av4[q].w};
            float bv[4] = {wv[q].x, wv[q].y, wv[q].z, wv[q].w};
            #pragma unroll
            for (int i = 0; i < 4; ++i)
                #pragma unroll
                for (int jj = 0; jj < 4; ++jj)
                    acc2[i][jj] = fmaf(av[i], bv[jj], acc2[i][jj]);
        }
    }
    #pragma unroll
    for (int jj = 0; jj < 4; ++jj) {
        float4 w;
        w.x = fmaxf(acc2[0][jj], 0.f); w.y = fmaxf(acc2[1][jj], 0.f);
        w.z = fmaxf(acc2[2][jj], 0.f); w.w = fmaxf(acc2[3][jj], 0.f);
        *(float4*)&h2w[(m * 4 + jj) * 17 + quad * 4] = w;
    }
    float acc3[4][2];
    {
        float2 bb = *(const float2*)&mb3[m * 2];
        #pragma unroll
        for (int i = 0; i < 4; ++i) { acc3[i][0] = bb.x; acc3[i][1] = bb.y; }
    }
    for (int cc = 0; cc < 64; cc += 8) {
        float2 wv[8]; float4 av4[8];
        #pragma unroll
        for (int q = 0; q < 8; ++q) wv[q] = *(const float2*)&mw3[(cc + q) * 32 + m * 2];
        #pragma unroll
        for (int q = 0; q < 8; ++q) av4[q] = *(const float4*)&h2w[(cc + q) * 17 + quad * 4];
        #pragma unroll
        for (int q = 0; q < 8; ++q) {
            float av[4] = {av4[q].x, av4[q].y, av4[q].z, av4[q].w};
            #pragma unroll
            for (int i = 0; i < 4; ++i) {
                acc3[i][0] = fmaf(av[i], wv[q].x, acc3[i][0]);
                acc3[i][1] = fmaf(av[i], wv[q].y, acc3[i][1]);
            }
        }
    }
    #pragma unroll
    for (int jj = 0; jj < 2; ++jj) {
        float4 w;
        w.x = fmaxf(acc3[0][jj], 0.f); w.y = fmaxf(acc3[1][jj], 0.f);
        w.z = fmaxf(acc3[2][jj], 0.f); w.w = fmaxf(acc3[3][jj], 0.f);
        *(float4*)&h3w[(m * 2 + jj) * 17 + quad * 4] = w;
    }
    if (lane < 16) {
        float z0 = mb4[0], z1 = mb4[1];
        #pragma unroll 8
        for (int c = 0; c < 32; ++c) {
            float h = h3w[c * 17 + lane];
            z0 = fmaf(h, mw4[c * 2 + 0], z0);
            z1 = fmaf(h, mw4[c * 2 + 1], z1);
        }
        float mx = fmaxf(z0, z1);
        float ls = mx + logf(expf(z0 - mx) + expf(z1 - mx));
        float2 o; o.x = z0 - ls; o.y = z1 - ls;
        *(float2*)&out[(size_t)(pw + lane) * 2] = o;
    }
}

extern "C" void kernel_launch(void* const* d_in, const int* in_sizes, int n_in,
                              void* d_out, int out_size, void* d_ws, size_t ws_size,
                              hipStream_t stream) {
    const float* x0   = (const float*)d_in[0];
    const float* c1w1 = (const float*)d_in[1];  const float* c1b1 = (const float*)d_in[2];
    const float* c1w2 = (const float*)d_in[3];  const float* c1b2 = (const float*)d_in[4];
    const float* c2w1 = (const float*)d_in[5];  const float* c2b1 = (const float*)d_in[6];
    const float* c2w2 = (const float*)d_in[7];  const float* c2b2 = (const float*)d_in[8];
    const float* c3w1 = (const float*)d_in[9];  const float* c3b1 = (const float*)d_in[10];
    const float* c3w2 = (const float*)d_in[11]; const float* c3b2 = (const float*)d_in[12];
    const float* mw1  = (const float*)d_in[13]; const float* mb1  = (const float*)d_in[14];
    const float* mw2  = (const float*)d_in[15]; const float* mb2  = (const float*)d_in[16];
    const float* mw3  = (const float*)d_in[17]; const float* mb3  = (const float*)d_in[18];
    const float* mw4  = (const float*)d_in[19]; const float* mb4  = (const float*)d_in[20];

    float* ws = (float*)d_ws;
    const size_t NF = (size_t)NPOINTS * 64;
    float* x1 = ws;                      // fp32 (uv L2 input)
    float* x2 = x1 + NF;                 // fp32 (uv L3 input)
    ushort_t* xh3 = (ushort_t*)(x2 + NF);
    ushort_t* xl3 = xh3 + NF;
    float* u  = (float*)(xl3 + NF);
    float* v  = u + NF;
    float* sq = v + NF;
    int*  idx = (int*)(sq + NPOINTS);
    ushort_t* xh1 = (ushort_t*)(idx + (size_t)NPOINTS * KNB);
    ushort_t* xl1 = xh1 + NF;
    ushort_t* xh2 = xl1 + NF;
    ushort_t* xl2 = xh2 + NF;
    ushort_t* w1fh = xl2 + NF;
    ushort_t* w1fl = w1fh + 128 * 192;
    ushort_t* w2fh = w1fl + 128 * 192;   // 3 layers x 4096
    ushort_t* w2fl = w2fh + 3 * 4096;
    float* wuv = (float*)(w2fl + 3 * 4096);  // 3 x 1024 fp32 layer-1 uv consts
    float* out = (float*)d_out;

    // ---- fused weight prep ----
    prep_kernel<<<145, 256, 0, stream>>>(mw1, c1w2, c2w2, c3w2, c1w1, c1b1,
                                         w1fh, w1fl, w2fh, w2fl, wuv);
    // ---- layer 1 (C_in = 1): sort-window knn + fused uv-free edge ----
    knn1_sort_kernel<<<NB, 256, 0, stream>>>(x0, idx);
    edge1_mfma_kernel<<<NB * 64, 256, 0, stream>>>(
        x0, idx, w2fh, w2fl, wuv, c1b2, x1, xh1, xl1, sq);
    // ---- layer 2: fused MFMA knn on xh1/xl1 (writes idx directly) ----
    knn_mfma_kernel<<<NB * 16, 256, 0, stream>>>(xh1, xl1, sq, idx);
    uv_gemm_kernel<<<NPOINTS / 64, 256, 0, stream>>>(x1, c2w1, c2b1, u, v);
    edge_mfma_kernel<true, true><<<NPOINTS / 16, 256, 0, stream>>>(
        u, v, idx, w2fh + 4096, w2fl + 4096, c2b2, x2, xh2, xl2, sq);
    // ---- layer 3: fused MFMA knn on xh2/xl2 ----
    knn_mfma_kernel<<<NB * 16, 256, 0, stream>>>(xh2, xl2, sq, idx);
    uv_gemm_kernel<<<NPOINTS / 64, 256, 0, stream>>>(x2, c3w1, c3b1, u, v);
    edge_mfma_kernel<false, false><<<NPOINTS / 16, 256, 0, stream>>>(
        u, v, idx, w2fh + 8192, w2fl + 8192, c3b2, nullptr, xh3, xl3, nullptr);
    // ---- final MLP + log_softmax ----
    mlp_kernel<<<NPOINTS / 32, 128, 0, stream>>>(xh1, xl1, xh2, xl2, xh3, xl3,
                                                 w1fh, w1fl, mb1, mw2, mb2,
                                                 mw3, mb3, mw4, mb4, out);
}

// Round 19
// 531.767 us; speedup vs baseline: 1.1167x; 1.0425x over previous
//
#include <hip/hip_runtime.h>
#include <math.h>

typedef unsigned short ushort_t;
typedef unsigned int uint_t;
typedef unsigned long long u64_t;
typedef __bf16 bf16x8_t __attribute__((ext_vector_type(8)));
typedef float f32x4_t __attribute__((ext_vector_type(4)));

static constexpr int NPTS = 1024;
static constexpr int NB = 64;
static constexpr int NPOINTS = NB * NPTS;   // 65536
static constexpr int KNB = 16;

__device__ __forceinline__ ushort_t f2bf(float f) {
    uint_t u = __float_as_uint(f);
    uint_t r = (u + 0x7FFFu + ((u >> 16) & 1u)) >> 16;
    return (ushort_t)r;
}
// pack distance (clamped >=0, 22 bits kept) + batch-local j (10 bits).
__device__ __forceinline__ uint_t packdj(float d, int j) {
    return (__float_as_uint(fmaxf(d, 0.f)) & 0xFFFFFC00u) | (uint_t)j;
}
// single-instruction median: for sorted L[k-1]<=L[k], post-insert
// L'[k] = med3(L[k-1], L[k], c). One VOP3 per step; all steps independent.
__device__ __forceinline__ uint_t med3u(uint_t a, uint_t b, uint_t c) {
    uint_t d;
    asm("v_med3_u32 %0, %1, %2, %3" : "=v"(d) : "v"(a), "v"(b), "v"(c));
    return d;
}
__device__ __forceinline__ void insert16(uint_t* L, uint_t c) {
    #pragma unroll
    for (int k = 15; k > 0; --k)
        L[k] = med3u(L[k - 1], L[k], c);
    L[0] = L[0] < c ? L[0] : c;
}
// monotone float->uint order transform
__device__ __forceinline__ uint_t f2ord(float f) {
    uint_t u = __float_as_uint(f);
    return (u & 0x80000000u) ? ~u : (u ^ 0x80000000u);
}

// ---------------- fused weight prep ----------------
// blocks 0..95   : mlp w1 frags (24576)
// blocks 96..143 : 3x edge w2 frags (4096 each)
// block  144     : layer-1 uv scalar consts (3072 floats)
// blocks 145..208: 2x uv [wd|wb] frags for layers 2/3 (8192 each)
__global__ __launch_bounds__(256) void prep_kernel(const float* __restrict__ mw1,
                                                   const float* __restrict__ c1w2,
                                                   const float* __restrict__ c2w2,
                                                   const float* __restrict__ c3w2,
                                                   const float* __restrict__ c1w1,
                                                   const float* __restrict__ c1b1,
                                                   const float* __restrict__ c2w1,
                                                   const float* __restrict__ c3w1,
                                                   ushort_t* __restrict__ w1fh,
                                                   ushort_t* __restrict__ w1fl,
                                                   ushort_t* __restrict__ w2fh,
                                                   ushort_t* __restrict__ w2fl,
                                                   float* __restrict__ wuv,
                                                   ushort_t* __restrict__ wuvfh,
                                                   ushort_t* __restrict__ wuvfl) {
    int blk = blockIdx.x;
    if (blk < 96) {
        int t = blk * 256 + threadIdx.x;         // 0..24575
        int e = t & 7;
        int lane = (t >> 3) & 63;
        int fs = t >> 9;                         // frag id = nt*6+ks, 0..47
        int nt = fs / 6, ks = fs - nt * 6;
        int m = lane & 15, quad = lane >> 4;
        int k = ks * 32 + quad * 8 + e;
        int n = nt * 16 + m;
        float w = mw1[k * 128 + n];
        uint_t bits = __float_as_uint(w);
        float hif = __uint_as_float(bits & 0xFFFF0000u);
        w1fh[t] = (ushort_t)(bits >> 16);
        w1fl[t] = f2bf(w - hif);
    } else if (blk < 144) {
        int layer = (blk - 96) >> 4;             // 0..2
        const float* w2 = layer == 0 ? c1w2 : (layer == 1 ? c2w2 : c3w2);
        int t = ((blk - 96) & 15) * 256 + threadIdx.x;   // 0..4095
        int e = t & 7;
        int lane = (t >> 3) & 63;
        int fs = t >> 9;                         // frag id = ct*2+kh, 0..7
        int ct = fs >> 1, kh = fs & 1;
        int m = lane & 15, quad = lane >> 4;
        int k = kh * 32 + quad * 8 + e;
        int n = ct * 16 + m;
        float w = w2[k * 64 + n];
        uint_t bits = __float_as_uint(w);
        float hif = __uint_as_float(bits & 0xFFFF0000u);
        w2fh[layer * 4096 + t] = (ushort_t)(bits >> 16);
        w2fl[layer * 4096 + t] = f2bf(w - hif);
    } else if (blk == 144) {
        // layer-1 uv constants: wuv[arr*1024 + lane*16 + kh*8 + e]
        for (int s = threadIdx.x; s < 3072; s += 256) {
            int arr = s >> 10, r = s & 1023;
            int lane = r >> 4, ce = r & 15;
            int kh = ce >> 3, e = ce & 7;
            int quad = lane >> 4;
            int c = kh * 32 + quad * 8 + e;
            float val = (arr == 0) ? (c1w1[c] - c1w1[64 + c])
                      : (arr == 1) ? c1w1[64 + c] : c1b1[c];
            wuv[s] = val;
        }
    } else {
        // uv B-frags: B[n][k], n<64: wd = w1a-w1b, n>=64: wb = w1b
        int layer = (blk - 145) >> 5;            // 0 -> c2w1, 1 -> c3w1
        const float* w1 = layer == 0 ? c2w1 : c3w1;
        int t = ((blk - 145) & 31) * 256 + threadIdx.x;  // 0..8191
        int e = t & 7;
        int lane = (t >> 3) & 63;
        int fs = t >> 9;                         // frag id = nt*2+ks, 0..15
        int nt = fs >> 1, ks = fs & 1;
        int m = lane & 15, quad = lane >> 4;
        int k = ks * 32 + quad * 8 + e;
        float w;
        if (nt < 4) {
            int n = nt * 16 + m;
            w = w1[k * 64 + n] - w1[(64 + k) * 64 + n];
        } else {
            int n = (nt - 4) * 16 + m;
            w = w1[(64 + k) * 64 + n];
        }
        uint_t bits = __float_as_uint(w);
        float hif = __uint_as_float(bits & 0xFFFF0000u);
        wuvfh[layer * 8192 + t] = (ushort_t)(bits >> 16);
        wuvfl[layer * 8192 + t] = f2bf(w - hif);
    }
}

// ---------------- layer-1 knn (C=1): bitonic sort + +/-16 window ----------------
__global__ __launch_bounds__(256) void knn1_sort_kernel(const float* __restrict__ pts,
                                                        int* __restrict__ idx_out) {
    __shared__ u64_t keys[NPTS];
    int b = blockIdx.x;
    int t = threadIdx.x;
    const float* base = pts + (size_t)b * NPTS;
    for (int s = t; s < NPTS; s += 256)
        keys[s] = ((u64_t)f2ord(base[s]) << 32) | (uint_t)s;
    for (int k = 2; k <= NPTS; k <<= 1) {
        for (int j2 = k >> 1; j2 > 0; j2 >>= 1) {
            __syncthreads();
            for (int i = t; i < NPTS; i += 256) {
                int ix = i ^ j2;
                if (ix > i) {
                    bool asc = ((i & k) == 0);
                    u64_t a = keys[i], c = keys[ix];
                    if ((a > c) == asc) { keys[i] = c; keys[ix] = a; }
                }
            }
        }
    }
    __syncthreads();
    for (int s = t; s < NPTS; s += 256) {
        u64_t me = keys[s];
        int jme = (int)(me & 0x3FFu);
        uint_t mo = (uint_t)(me >> 32);
        uint_t mu = (mo & 0x80000000u) ? (mo ^ 0x80000000u) : ~mo;
        float xs = __uint_as_float(mu);
        uint_t lst[KNB];
        #pragma unroll
        for (int k = 0; k < KNB; ++k) lst[k] = 0xFFFFFFFFu;
        int lo = s - 16; if (lo < 0) lo = 0;
        int hi = s + 16; if (hi > NPTS - 1) hi = NPTS - 1;
        for (int q = lo; q <= hi; ++q) {
            u64_t o = keys[q];
            uint_t oo = (uint_t)(o >> 32);
            uint_t ou = (oo & 0x80000000u) ? (oo ^ 0x80000000u) : ~oo;
            float xo = __uint_as_float(ou);
            float d = (xs - xo) * (xs - xo);
            insert16(lst, packdj(d, (int)(o & 0x3FFu)));
        }
        int* op = idx_out + ((size_t)b * NPTS + jme) * KNB;
        #pragma unroll
        for (int k = 0; k < KNB; ++k) op[k] = (int)(lst[k] & 0x3FFu);
    }
}

// ---------------- MFMA knn (C=64), FUSED: block = (batch, i-block), wave = chunk ----
__global__ __launch_bounds__(256, 4) void knn_mfma_kernel(const ushort_t* __restrict__ xh,
                                                          const ushort_t* __restrict__ xl,
                                                          const float* __restrict__ sq,
                                                          int* __restrict__ idx_out) {
    constexpr int JC = NPTS / 4;                 // 256 j per chunk(=wave)
    __shared__ uint_t dbuf[4][16 * 68];
    __shared__ float sqs[4][JC];
    __shared__ uint_t mlst[4][64][17];           // [chunk][i-lane][k], stride-17
    int b    = blockIdx.x & 63;
    int ib   = blockIdx.x >> 6;                  // 0..15
    int wave = threadIdx.x >> 6;                 // = chunk
    int lane = threadIdx.x & 63;
    int i0   = b * NPTS + ib * 64;
    int m = lane & 15, quad = lane >> 4;
    int j0c = wave * JC;

    for (int t = lane; t < JC; t += 64) sqs[wave][t] = sq[b * NPTS + j0c + t];

    bf16x8_t Ah[4][2], Al[4][2];
    #pragma unroll
    for (int it = 0; it < 4; ++it) {
        #pragma unroll
        for (int kh = 0; kh < 2; ++kh) {
            size_t off = ((size_t)(i0 + it * 16 + m)) * 64 + kh * 32 + quad * 8;
            Ah[it][kh] = *(const bf16x8_t*)(xh + off);
            Al[it][kh] = *(const bf16x8_t*)(xl + off);
        }
    }
    float4 sqi[4];
    #pragma unroll
    for (int it = 0; it < 4; ++it)
        sqi[it] = *(const float4*)&sq[i0 + it * 16 + quad * 4];

    uint_t lst[KNB];
    #pragma unroll
    for (int k = 0; k < KNB; ++k) lst[k] = 0xFFFFFFFFu;

    for (int g = 0; g < JC / 16; ++g) {
        int jg = j0c + g * 16;                       // batch-local j base
        size_t boff = ((size_t)(b * NPTS + jg + m)) * 64 + quad * 8;
        bf16x8_t Bh0 = *(const bf16x8_t*)(xh + boff);
        bf16x8_t Bh1 = *(const bf16x8_t*)(xh + boff + 32);
        bf16x8_t Bl0 = *(const bf16x8_t*)(xl + boff);
        bf16x8_t Bl1 = *(const bf16x8_t*)(xl + boff + 32);
        float sqj = sqs[wave][g * 16 + m];
        int jm = jg + m;
        #pragma unroll
        for (int it = 0; it < 4; ++it) {
            f32x4_t acc = {0.f, 0.f, 0.f, 0.f};
            acc = __builtin_amdgcn_mfma_f32_16x16x32_bf16(Ah[it][0], Bh0, acc, 0, 0, 0);
            acc = __builtin_amdgcn_mfma_f32_16x16x32_bf16(Ah[it][1], Bh1, acc, 0, 0, 0);
            acc = __builtin_amdgcn_mfma_f32_16x16x32_bf16(Ah[it][0], Bl0, acc, 0, 0, 0);
            acc = __builtin_amdgcn_mfma_f32_16x16x32_bf16(Ah[it][1], Bl1, acc, 0, 0, 0);
            acc = __builtin_amdgcn_mfma_f32_16x16x32_bf16(Al[it][0], Bh0, acc, 0, 0, 0);
            acc = __builtin_amdgcn_mfma_f32_16x16x32_bf16(Al[it][1], Bh1, acc, 0, 0, 0);
            uint4 pv;
            pv.x = packdj(sqi[it].x + sqj - 2.0f * acc[0], jm);
            pv.y = packdj(sqi[it].y + sqj - 2.0f * acc[1], jm);
            pv.z = packdj(sqi[it].z + sqj - 2.0f * acc[2], jm);
            pv.w = packdj(sqi[it].w + sqj - 2.0f * acc[3], jm);
            *(uint4*)&dbuf[wave][m * 68 + it * 16 + quad * 4] = pv;
        }
        // dbuf is wave-private: ds-ordering within the wave, no barrier.
        #pragma unroll
        for (int jj = 0; jj < 16; ++jj)
            insert16(lst, dbuf[wave][jj * 68 + lane]);
    }
    #pragma unroll
    for (int k = 0; k < KNB; ++k) mlst[wave][lane][k] = lst[k];
    __syncthreads();
    if (wave == 0) {
        uint_t fin[KNB];
        #pragma unroll
        for (int k = 0; k < KNB; ++k) fin[k] = 0xFFFFFFFFu;
        #pragma unroll
        for (int c = 0; c < 4; ++c)
            #pragma unroll
            for (int k = 0; k < KNB; ++k)
                insert16(fin, mlst[c][lane][k]);
        int* op = idx_out + (size_t)(i0 + lane) * KNB;
        #pragma unroll
        for (int k = 0; k < KNB; ++k) op[k] = (int)(fin[k] & 0x3FFu);
    }
}

// ---------------- uv via MFMA: M=points, N=128=[u|v], K=64, hi/lo from xh/xl ----------------
// wave = 16 points; 2 k-steps x 8 n-tiles x 3 terms = 48 MFMAs.
__global__ __launch_bounds__(256) void uv_mfma_kernel(const ushort_t* __restrict__ xh,
                                                      const ushort_t* __restrict__ xl,
                                                      const ushort_t* __restrict__ wufh,
                                                      const ushort_t* __restrict__ wufl,
                                                      const float* __restrict__ b1,
                                                      float* __restrict__ u,
                                                      float* __restrict__ v) {
    int wave = threadIdx.x >> 6, lane = threadIdx.x & 63;
    int m = lane & 15, quad = lane >> 4;
    int b = blockIdx.x & 63;                    // XCD-pinned batch
    int r = blockIdx.x >> 6;                    // 0..15
    int p0 = b * NPTS + r * 64 + wave * 16;
    bf16x8_t Ah[2], Al[2];
    #pragma unroll
    for (int ks = 0; ks < 2; ++ks) {
        size_t aoff = (size_t)(p0 + m) * 64 + ks * 32 + quad * 8;
        Ah[ks] = *(const bf16x8_t*)(xh + aoff);
        Al[ks] = *(const bf16x8_t*)(xl + aoff);
    }
    f32x4_t acc[8];
    #pragma unroll
    for (int nt = 0; nt < 8; ++nt) acc[nt] = (f32x4_t){0.f, 0.f, 0.f, 0.f};
    #pragma unroll
    for (int ks = 0; ks < 2; ++ks) {
        #pragma unroll
        for (int nt = 0; nt < 8; ++nt) {
            size_t boff = (size_t)((nt * 2 + ks) * 64 + lane) * 8;
            bf16x8_t Bh = *(const bf16x8_t*)(wufh + boff);
            bf16x8_t Bl = *(const bf16x8_t*)(wufl + boff);
            acc[nt] = __builtin_amdgcn_mfma_f32_16x16x32_bf16(Ah[ks], Bh, acc[nt], 0, 0, 0);
            acc[nt] = __builtin_amdgcn_mfma_f32_16x16x32_bf16(Ah[ks], Bl, acc[nt], 0, 0, 0);
            acc[nt] = __builtin_amdgcn_mfma_f32_16x16x32_bf16(Al[ks], Bh, acc[nt], 0, 0, 0);
        }
    }
    // C: row = quad*4+reg = point-in-wave, col = m = n-in-tile
    #pragma unroll
    for (int nt = 0; nt < 8; ++nt) {
        int ch = (nt & 3) * 16 + m;
        float bb = (nt < 4) ? b1[ch] : 0.f;
        float* dst = (nt < 4) ? u : v;
        #pragma unroll
        for (int rr = 0; rr < 4; ++rr) {
            int p = p0 + quad * 4 + rr;
            dst[(size_t)p * 64 + ch] = acc[nt][rr] + bb;
        }
    }
}

// ---------------- edge1 MFMA (layer 1, C_in=1): u/v never materialized ----------------
__global__ __launch_bounds__(256) void edge1_mfma_kernel(const float* __restrict__ x0,
                                                         const int* __restrict__ idx,
                                                         const ushort_t* __restrict__ w2fh,
                                                         const ushort_t* __restrict__ w2fl,
                                                         const float* __restrict__ wuv,
                                                         const float* __restrict__ b2,
                                                         ushort_t* __restrict__ oh,
                                                         ushort_t* __restrict__ ol,
                                                         float* __restrict__ sqout) {
    int wave = threadIdx.x >> 6, lane = threadIdx.x & 63;
    int m = lane & 15, quad = lane >> 4;
    bf16x8_t Bh[4][2], Bl[4][2];
    #pragma unroll
    for (int ct = 0; ct < 4; ++ct) {
        #pragma unroll
        for (int kh = 0; kh < 2; ++kh) {
            size_t boff = (size_t)((ct * 2 + kh) * 64 + lane) * 8;
            Bh[ct][kh] = *(const bf16x8_t*)(w2fh + boff);
            Bl[ct][kh] = *(const bf16x8_t*)(w2fl + boff);
        }
    }
    float wdv[16], wbv[16], bbv[16];
    #pragma unroll
    for (int q = 0; q < 4; ++q) {
        *(float4*)&wdv[q * 4] = *(const float4*)&wuv[lane * 16 + q * 4];
        *(float4*)&wbv[q * 4] = *(const float4*)&wuv[1024 + lane * 16 + q * 4];
        *(float4*)&bbv[q * 4] = *(const float4*)&wuv[2048 + lane * 16 + q * 4];
    }
    float bias[4];
    #pragma unroll
    for (int ct = 0; ct < 4; ++ct) bias[ct] = b2[ct * 16 + m];
    int bb_ = blockIdx.x & 63;                  // batch (XCD-pinned)
    int r_  = blockIdx.x >> 6;                  // 0..63 within batch
    int p0 = bb_ * NPTS + r_ * 16 + wave * 4;
    int jv[4];
    #pragma unroll
    for (int pi = 0; pi < 4; ++pi) jv[pi] = idx[(p0 + pi) * 16 + m];
    float xj4[4];
    #pragma unroll
    for (int pi = 0; pi < 4; ++pi) xj4[pi] = x0[(bb_ << 10) + jv[pi]];
    #pragma unroll
    for (int pi = 0; pi < 4; ++pi) {
        int p = p0 + pi;
        float xi = x0[p];                       // wave-uniform
        float xj = xj4[pi];                     // per A-row (neighbor m)
        bf16x8_t Ah[2], Al[2];
        #pragma unroll
        for (int kh = 0; kh < 2; ++kh) {
            union { ushort_t s[8]; bf16x8_t v8; } H, L;
            #pragma unroll
            for (int e = 0; e < 8; ++e) {
                int ce = kh * 8 + e;
                float g = fmaxf(fmaf(xi, wdv[ce], fmaf(xj, wbv[ce], bbv[ce])), 0.f);
                uint_t bits = __float_as_uint(g);
                H.s[e] = (ushort_t)(bits >> 16);
                float hif = __uint_as_float(bits & 0xFFFF0000u);
                L.s[e] = (ushort_t)(__float_as_uint(g - hif) >> 16);
            }
            Ah[kh] = H.v8; Al[kh] = L.v8;
        }
        float val[4];
        #pragma unroll
        for (int ct = 0; ct < 4; ++ct) {
            f32x4_t acc = {0.f, 0.f, 0.f, 0.f};
            acc = __builtin_amdgcn_mfma_f32_16x16x32_bf16(Ah[0], Bh[ct][0], acc, 0, 0, 0);
            acc = __builtin_amdgcn_mfma_f32_16x16x32_bf16(Ah[1], Bh[ct][1], acc, 0, 0, 0);
            acc = __builtin_amdgcn_mfma_f32_16x16x32_bf16(Ah[0], Bl[ct][0], acc, 0, 0, 0);
            acc = __builtin_amdgcn_mfma_f32_16x16x32_bf16(Ah[1], Bl[ct][1], acc, 0, 0, 0);
            acc = __builtin_amdgcn_mfma_f32_16x16x32_bf16(Al[0], Bh[ct][0], acc, 0, 0, 0);
            acc = __builtin_amdgcn_mfma_f32_16x16x32_bf16(Al[1], Bh[ct][1], acc, 0, 0, 0);
            float mm = fmaxf(fmaxf(acc[0], acc[1]), fmaxf(acc[2], acc[3]));
            mm = fmaxf(mm, __shfl_xor(mm, 16, 64));
            mm = fmaxf(mm, __shfl_xor(mm, 32, 64));
            val[ct] = mm + bias[ct];
        }
        {   // fused sqnorm
            float partial = val[0] * val[0] + val[1] * val[1]
                          + val[2] * val[2] + val[3] * val[3];
            partial += __shfl_xor(partial, 1, 64);
            partial += __shfl_xor(partial, 2, 64);
            partial += __shfl_xor(partial, 4, 64);
            partial += __shfl_xor(partial, 8, 64);
            if (lane == 0) sqout[p] = partial;
        }
        if (quad == 0) {
            #pragma unroll
            for (int ct = 0; ct < 4; ++ct) {
                int o = ct * 16 + m;
                float vv = val[ct];
                uint_t bits = __float_as_uint(vv);
                oh[(size_t)p * 64 + o] = (ushort_t)(bits >> 16);
                float hif = __uint_as_float(bits & 0xFFFF0000u);
                ol[(size_t)p * 64 + o] = f2bf(vv - hif);
            }
        }
    }
}

// ---------------- edge MFMA (layers 2/3): wave = 1 point/step, prefab w2 frags ----
template<bool WSQ>
__global__ __launch_bounds__(256) void edge_mfma_kernel(const float* __restrict__ u,
                                                        const float* __restrict__ v,
                                                        const int* __restrict__ idx,
                                                        const ushort_t* __restrict__ w2fh,
                                                        const ushort_t* __restrict__ w2fl,
                                                        const float* __restrict__ b2,
                                                        ushort_t* __restrict__ oh,
                                                        ushort_t* __restrict__ ol,
                                                        float* __restrict__ sqout) {
    int wave = threadIdx.x >> 6, lane = threadIdx.x & 63;
    int m = lane & 15, quad = lane >> 4;
    bf16x8_t Bh[4][2], Bl[4][2];
    #pragma unroll
    for (int ct = 0; ct < 4; ++ct) {
        #pragma unroll
        for (int kh = 0; kh < 2; ++kh) {
            size_t boff = (size_t)((ct * 2 + kh) * 64 + lane) * 8;
            Bh[ct][kh] = *(const bf16x8_t*)(w2fh + boff);
            Bl[ct][kh] = *(const bf16x8_t*)(w2fl + boff);
        }
    }
    float bias[4];
    #pragma unroll
    for (int ct = 0; ct < 4; ++ct) bias[ct] = b2[ct * 16 + m];
    int bb_ = blockIdx.x & 63;                  // batch (XCD-pinned)
    int r_  = blockIdx.x >> 6;                  // 0..63 within batch
    int p0 = bb_ * NPTS + r_ * 16 + wave * 4;
    int jv[4];
    #pragma unroll
    for (int pi = 0; pi < 4; ++pi) jv[pi] = idx[(p0 + pi) * 16 + m];
    #pragma unroll
    for (int pi = 0; pi < 4; ++pi) {
        int p = p0 + pi;
        const float* up = u + (size_t)p * 64;
        const float* vp = v + ((size_t)(bb_ << 10) + jv[pi]) * 64;
        bf16x8_t Ah[2], Al[2];
        #pragma unroll
        for (int kh = 0; kh < 2; ++kh) {
            int c0 = kh * 32 + quad * 8;
            float4 ua = *(const float4*)(up + c0);
            float4 ub = *(const float4*)(up + c0 + 4);
            float4 va = *(const float4*)(vp + c0);
            float4 vb = *(const float4*)(vp + c0 + 4);
            float f[8] = {ua.x + va.x, ua.y + va.y, ua.z + va.z, ua.w + va.w,
                          ub.x + vb.x, ub.y + vb.y, ub.z + vb.z, ub.w + vb.w};
            union { ushort_t s[8]; bf16x8_t v8; } H, L;
            #pragma unroll
            for (int e = 0; e < 8; ++e) {
                float g = fmaxf(f[e], 0.f);
                uint_t bits = __float_as_uint(g);
                H.s[e] = (ushort_t)(bits >> 16);
                float hif = __uint_as_float(bits & 0xFFFF0000u);
                L.s[e] = (ushort_t)(__float_as_uint(g - hif) >> 16);
            }
            Ah[kh] = H.v8; Al[kh] = L.v8;
        }
        float val[4];
        #pragma unroll
        for (int ct = 0; ct < 4; ++ct) {
            f32x4_t acc = {0.f, 0.f, 0.f, 0.f};
            acc = __builtin_amdgcn_mfma_f32_16x16x32_bf16(Ah[0], Bh[ct][0], acc, 0, 0, 0);
            acc = __builtin_amdgcn_mfma_f32_16x16x32_bf16(Ah[1], Bh[ct][1], acc, 0, 0, 0);
            acc = __builtin_amdgcn_mfma_f32_16x16x32_bf16(Ah[0], Bl[ct][0], acc, 0, 0, 0);
            acc = __builtin_amdgcn_mfma_f32_16x16x32_bf16(Ah[1], Bl[ct][1], acc, 0, 0, 0);
            acc = __builtin_amdgcn_mfma_f32_16x16x32_bf16(Al[0], Bh[ct][0], acc, 0, 0, 0);
            acc = __builtin_amdgcn_mfma_f32_16x16x32_bf16(Al[1], Bh[ct][1], acc, 0, 0, 0);
            float mm = fmaxf(fmaxf(acc[0], acc[1]), fmaxf(acc[2], acc[3]));
            mm = fmaxf(mm, __shfl_xor(mm, 16, 64));
            mm = fmaxf(mm, __shfl_xor(mm, 32, 64));   // mm now quad-uniform
            val[ct] = mm + bias[ct];
        }
        if constexpr (WSQ) {
            float partial = val[0] * val[0] + val[1] * val[1]
                          + val[2] * val[2] + val[3] * val[3];
            partial += __shfl_xor(partial, 1, 64);
            partial += __shfl_xor(partial, 2, 64);
            partial += __shfl_xor(partial, 4, 64);
            partial += __shfl_xor(partial, 8, 64);
            if (lane == 0) sqout[p] = partial;
        }
        if (quad == 0) {
            #pragma unroll
            for (int ct = 0; ct < 4; ++ct) {
                int o = ct * 16 + m;
                float vv = val[ct];
                uint_t bits = __float_as_uint(vv);
                oh[(size_t)p * 64 + o] = (ushort_t)(bits >> 16);
                float hif = __uint_as_float(bits & 0xFFFF0000u);
                ol[(size_t)p * 64 + o] = f2bf(vv - hif);
            }
        }
    }
}

// ---------------- final MLP: wave-private, barrier-free (converged structure) ----------------
__global__ __launch_bounds__(128, 2) void mlp_kernel(const ushort_t* __restrict__ xh1,
                                                  const ushort_t* __restrict__ xl1,
                                                  const ushort_t* __restrict__ xh2,
                                                  const ushort_t* __restrict__ xl2,
                                                  const ushort_t* __restrict__ xh3,
                                                  const ushort_t* __restrict__ xl3,
                                                  const ushort_t* __restrict__ w1fh,
                                                  const ushort_t* __restrict__ w1fl,
                                                  const float* __restrict__ mb1,
                                                  const float* __restrict__ mw2, const float* __restrict__ mb2,
                                                  const float* __restrict__ mw3, const float* __restrict__ mb3,
                                                  const float* __restrict__ mw4, const float* __restrict__ mb4,
                                                  float* __restrict__ out) {
    __shared__ float smem[2][128 * 17];      // 8704 B per wave
    int wave = threadIdx.x >> 6, lane = threadIdx.x & 63;
    float* h1w = smem[wave];                 // [128][17]
    float* h2w = smem[wave];                 // [64][17]  overlays h1 (written after all h1 reads)
    float* h3w = smem[wave] + 64 * 17;       // [32][17]  overlays h1's upper half
    int m = lane & 15, quad = lane >> 4;
    int pw = blockIdx.x * 32 + wave * 16;    // this wave's 16 points

    const ushort_t* HS[3] = {xh1, xh2, xh3};
    const ushort_t* LS[3] = {xl1, xl2, xl3};
    bf16x8_t Ah[6], Al[6];
    #pragma unroll
    for (int ks = 0; ks < 6; ++ks) {
        size_t aoff = (size_t)(pw + m) * 64 + (ks & 1) * 32 + quad * 8;
        Ah[ks] = *(const bf16x8_t*)(HS[ks >> 1] + aoff);
        Al[ks] = *(const bf16x8_t*)(LS[ks >> 1] + aoff);
    }
    f32x4_t acc1[8];
    #pragma unroll
    for (int nt = 0; nt < 8; ++nt) acc1[nt] = (f32x4_t){0.f, 0.f, 0.f, 0.f};
    #pragma unroll
    for (int ks = 0; ks < 6; ++ks) {
        bf16x8_t Bh[8], Bl[8];
        #pragma unroll
        for (int nt = 0; nt < 8; ++nt) {
            size_t boff = (size_t)(nt * 6 + ks) * 512 + lane * 8;
            Bh[nt] = *(const bf16x8_t*)(w1fh + boff);
            Bl[nt] = *(const bf16x8_t*)(w1fl + boff);
        }
        #pragma unroll
        for (int nt = 0; nt < 8; ++nt) {
            acc1[nt] = __builtin_amdgcn_mfma_f32_16x16x32_bf16(Ah[ks], Bh[nt], acc1[nt], 0, 0, 0);
            acc1[nt] = __builtin_amdgcn_mfma_f32_16x16x32_bf16(Ah[ks], Bl[nt], acc1[nt], 0, 0, 0);
            acc1[nt] = __builtin_amdgcn_mfma_f32_16x16x32_bf16(Al[ks], Bh[nt], acc1[nt], 0, 0, 0);
        }
    }
    #pragma unroll
    for (int nt = 0; nt < 8; ++nt) {
        float bb = mb1[nt * 16 + m];
        float4 w;
        w.x = fmaxf(acc1[nt][0] + bb, 0.f);
        w.y = fmaxf(acc1[nt][1] + bb, 0.f);
        w.z = fmaxf(acc1[nt][2] + bb, 0.f);
        w.w = fmaxf(acc1[nt][3] + bb, 0.f);
        *(float4*)&h1w[(nt * 16 + m) * 17 + quad * 4] = w;
    }
    float acc2[4][4];
    {
        float4 bb = *(const float4*)&mb2[m * 4];
        #pragma unroll
        for (int i = 0; i < 4; ++i) {
            acc2[i][0] = bb.x; acc2[i][1] = bb.y; acc2[i][2] = bb.z; acc2[i][3] = bb.w;
        }
    }
    for (int cc = 0; cc < 128; cc += 8) {
        float4 wv[8], av4[8];
        #pragma unroll
        for (int q = 0; q < 8; ++q) wv[q] = *(const float4*)&mw2[(cc + q) * 64 + m * 4];
        #pragma unroll
        for (int q = 0; q < 8; ++q) av4[q] = *(const float4*)&h1w[(cc + q) * 17 + quad * 4];
        #pragma unroll
        for (int q = 0; q < 8; ++q) {
            float av[4] = {av4[q].x, av4[q].y, av4[q].z, av4[q].w};
            float bv[4] = {wv[q].x, wv[q].y, wv[q].z, wv[q].w};
            #pragma unroll
            for (int i = 0; i < 4; ++i)
                #pragma unroll
                for (int jj = 0; jj < 4; ++jj)
                    acc2[i][jj] = fmaf(av[i], bv[jj], acc2[i][jj]);
        }
    }
    #pragma unroll
    for (int jj = 0; jj < 4; ++jj) {
        float4 w;
        w.x = fmaxf(acc2[0][jj], 0.f); w.y = fmaxf(acc2[1][jj], 0.f);
        w.z = fmaxf(acc2[2][jj], 0.f); w.w = fmaxf(acc2[3][jj], 0.f);
        *(float4*)&h2w[(m * 4 + jj) * 17 + quad * 4] = w;
    }
    float acc3[4][2];
    {
        float2 bb = *(const float2*)&mb3[m * 2];
        #pragma unroll
        for (int i = 0; i < 4; ++i) { acc3[i][0] = bb.x; acc3[i][1] = bb.y; }
    }
    for (int cc = 0; cc < 64; cc += 8) {
        float2 wv[8]; float4 av4[8];
        #pragma unroll
        for (int q = 0; q < 8; ++q) wv[q] = *(const float2*)&mw3[(cc + q) * 32 + m * 2];
        #pragma unroll
        for (int q = 0; q < 8; ++q) av4[q] = *(const float4*)&h2w[(cc + q) * 17 + quad * 4];
        #pragma unroll
        for (int q = 0; q < 8; ++q) {
            float av[4] = {av4[q].x, av4[q].y, av4[q].z, av4[q].w};
            #pragma unroll
            for (int i = 0; i < 4; ++i) {
                acc3[i][0] = fmaf(av[i], wv[q].x, acc3[i][0]);
                acc3[i][1] = fmaf(av[i], wv[q].y, acc3[i][1]);
            }
        }
    }
    #pragma unroll
    for (int jj = 0; jj < 2; ++jj) {
        float4 w;
        w.x = fmaxf(acc3[0][jj], 0.f); w.y = fmaxf(acc3[1][jj], 0.f);
        w.z = fmaxf(acc3[2][jj], 0.f); w.w = fmaxf(acc3[3][jj], 0.f);
        *(float4*)&h3w[(m * 2 + jj) * 17 + quad * 4] = w;
    }
    if (lane < 16) {
        float z0 = mb4[0], z1 = mb4[1];
        #pragma unroll 8
        for (int c = 0; c < 32; ++c) {
            float h = h3w[c * 17 + lane];
            z0 = fmaf(h, mw4[c * 2 + 0], z0);
            z1 = fmaf(h, mw4[c * 2 + 1], z1);
        }
        float mx = fmaxf(z0, z1);
        float ls = mx + logf(expf(z0 - mx) + expf(z1 - mx));
        float2 o; o.x = z0 - ls; o.y = z1 - ls;
        *(float2*)&out[(size_t)(pw + lane) * 2] = o;
    }
}

extern "C" void kernel_launch(void* const* d_in, const int* in_sizes, int n_in,
                              void* d_out, int out_size, void* d_ws, size_t ws_size,
                              hipStream_t stream) {
    const float* x0   = (const float*)d_in[0];
    const float* c1w1 = (const float*)d_in[1];  const float* c1b1 = (const float*)d_in[2];
    const float* c1w2 = (const float*)d_in[3];  const float* c1b2 = (const float*)d_in[4];
    const float* c2w1 = (const float*)d_in[5];  const float* c2b1 = (const float*)d_in[6];
    const float* c2w2 = (const float*)d_in[7];  const float* c2b2 = (const float*)d_in[8];
    const float* c3w1 = (const float*)d_in[9];  const float* c3b1 = (const float*)d_in[10];
    const float* c3w2 = (const float*)d_in[11]; const float* c3b2 = (const float*)d_in[12];
    const float* mw1  = (const float*)d_in[13]; const float* mb1  = (const float*)d_in[14];
    const float* mw2  = (const float*)d_in[15]; const float* mb2  = (const float*)d_in[16];
    const float* mw3  = (const float*)d_in[17]; const float* mb3  = (const float*)d_in[18];
    const float* mw4  = (const float*)d_in[19]; const float* mb4  = (const float*)d_in[20];

    float* ws = (float*)d_ws;
    const size_t NF = (size_t)NPOINTS * 64;
    float* u  = ws;
    float* v  = u + NF;
    float* sq = v + NF;
    int*  idx = (int*)(sq + NPOINTS);
    ushort_t* xh1 = (ushort_t*)(idx + (size_t)NPOINTS * KNB);
    ushort_t* xl1 = xh1 + NF;
    ushort_t* xh2 = xl1 + NF;
    ushort_t* xl2 = xh2 + NF;
    ushort_t* xh3 = xl2 + NF;
    ushort_t* xl3 = xh3 + NF;
    ushort_t* w1fh = xl3 + NF;
    ushort_t* w1fl = w1fh + 128 * 192;
    ushort_t* w2fh = w1fl + 128 * 192;       // 3 layers x 4096
    ushort_t* w2fl = w2fh + 3 * 4096;
    float* wuv = (float*)(w2fl + 3 * 4096);  // 3 x 1024 fp32 layer-1 uv consts
    ushort_t* wuvfh = (ushort_t*)(wuv + 3072);   // 2 layers x 8192
    ushort_t* wuvfl = wuvfh + 2 * 8192;
    float* out = (float*)d_out;

    // ---- fused weight prep ----
    prep_kernel<<<209, 256, 0, stream>>>(mw1, c1w2, c2w2, c3w2, c1w1, c1b1,
                                         c2w1, c3w1, w1fh, w1fl, w2fh, w2fl,
                                         wuv, wuvfh, wuvfl);
    // ---- layer 1 (C_in = 1): sort-window knn + uv-free edge ----
    knn1_sort_kernel<<<NB, 256, 0, stream>>>(x0, idx);
    edge1_mfma_kernel<<<NB * 64, 256, 0, stream>>>(
        x0, idx, w2fh, w2fl, wuv, c1b2, xh1, xl1, sq);
    // ---- layer 2: fused MFMA knn + MFMA uv + edge ----
    knn_mfma_kernel<<<NB * 16, 256, 0, stream>>>(xh1, xl1, sq, idx);
    uv_mfma_kernel<<<NB * 16, 256, 0, stream>>>(xh1, xl1, wuvfh, wuvfl, c2b1, u, v);
    edge_mfma_kernel<true><<<NPOINTS / 16, 256, 0, stream>>>(
        u, v, idx, w2fh + 4096, w2fl + 4096, c2b2, xh2, xl2, sq);
    // ---- layer 3 ----
    knn_mfma_kernel<<<NB * 16, 256, 0, stream>>>(xh2, xl2, sq, idx);
    uv_mfma_kernel<<<NB * 16, 256, 0, stream>>>(xh2, xl2, wuvfh + 8192, wuvfl + 8192,
                                                c3b1, u, v);
    edge_mfma_kernel<false><<<NPOINTS / 16, 256, 0, stream>>>(
        u, v, idx, w2fh + 8192, w2fl + 8192, c3b2, xh3, xl3, nullptr);
    // ---- final MLP + log_softmax ----
    mlp_kernel<<<NPOINTS / 32, 128, 0, stream>>>(xh1, xl1, xh2, xl2, xh3, xl3,
                                                 w1fh, w1fl, mb1, mw2, mb2,
                                                 mw3, mb3, mw4, mb4, out);
}